// Round 16
// baseline (5495.033 us; speedup 1.0000x reference)
//
#include <hip/hip_runtime.h>
#include <stdint.h>

#define B_ 16
#define T_ 600
#define S_ 600
#define D_ 1024
#define H_ 8
#define HD_ 128
#define L_ 8
#define DFF_ 4096
#define IN_ 52
#define TP1 601
#define MTOK 9600   // B*T
#define MPAD 9728   // 38*256 padded rows
#define VTK 608     // padded key count for V^T

typedef unsigned short u16;
typedef float f32x4 __attribute__((ext_vector_type(4)));
typedef __bf16 bf16x8 __attribute__((ext_vector_type(8)));

__device__ __forceinline__ u16 f2bf(float f){
  union { float f; unsigned u; } v; v.f = f;
  v.u += 0x7FFFu + ((v.u >> 16) & 1u);
  return (u16)(v.u >> 16);
}
__device__ __forceinline__ float bf2f(u16 h){
  union { unsigned u; float f; } v; v.u = ((unsigned)h) << 16;
  return v.f;
}
__device__ __forceinline__ void gld_lds16(const void* g, void* l){
  __builtin_amdgcn_global_load_lds(
      (const __attribute__((address_space(1))) void*)(uintptr_t)g,
      (__attribute__((address_space(3))) void*)(uintptr_t)l, 16, 0, 0);
}
__device__ __forceinline__ f32x4 MM(bf16x8 a, bf16x8 b, f32x4 c){
  return __builtin_amdgcn_mfma_f32_16x16x32_bf16(a, b, c, 0, 0, 0);
}
#define BAR() asm volatile("s_barrier" ::: "memory")

// =============== 256x256 GEMM, BK=64, 8 waves, early-issue schedule ============
// EPI: 0 = bf16 out, 1 = relu+bf16. Epilogue: C tile packed to LDS (128KB) then
// full-line uint4 stores.
template<int EPI>
__global__ __launch_bounds__(512, 2)
void k_gemm256(const u16* __restrict__ A, const u16* __restrict__ W,
               const float* __restrict__ bias, void* __restrict__ Cout,
               int N, int K){
  __shared__ u16 lds[65536];                 // 128 KiB: 2 bufs x (A 16384 + B 16384) u16
  const int t = threadIdx.x;
  const int w = t >> 6, l = t & 63;
  const int lr = l & 15, lg = l >> 4;
  const int wr = w >> 2, wc = w & 3;

  int lin = blockIdx.y * gridDim.x + blockIdx.x;
  const int nwg = gridDim.x * gridDim.y;
  lin = (lin & 7) * (nwg >> 3) + (lin >> 3);
  const long m0 = (long)(lin / gridDim.x) * 256;
  const long n0 = (long)(lin % gridDim.x) * 256;

  const int srow = w*8 + (l >> 3);
  const int schk = (l & 7) ^ (l >> 3);
  const u16* gA = A + (m0 + srow) * (long)K + schk * 8;
  const u16* gB = W + (n0 + srow) * (long)K + schk * 8;

  const int chk0 = ((    lg) ^ (lr & 7)) * 8;
  const int chk1 = ((4 + lg) ^ (lr & 7)) * 8;
  const int arow = (wr*128 + lr) * 64;
  const int brow = (wc*64  + lr) * 64 + 16384;

  f32x4 acc[8][4] = {};
  const int NT = K >> 6;

#define STG_A(i) gld_lds16(gA + (long)(i)*64*K + nc, (void*)(lds + nb + (i)*4096 + w*512))
#define STG_B(i) gld_lds16(gB + (long)(i)*64*K + nc, (void*)(lds + nb + 16384 + (i)*4096 + w*512))
#define LOADF(mq, CH) \
    a0 = *(const bf16x8*)(lds + bufo + arow + ((mq)*4+0)*1024 + (CH)); \
    a1 = *(const bf16x8*)(lds + bufo + arow + ((mq)*4+1)*1024 + (CH)); \
    a2 = *(const bf16x8*)(lds + bufo + arow + ((mq)*4+2)*1024 + (CH)); \
    a3 = *(const bf16x8*)(lds + bufo + arow + ((mq)*4+3)*1024 + (CH)); \
    b0 = *(const bf16x8*)(lds + bufo + brow + 0*1024 + (CH)); \
    b1 = *(const bf16x8*)(lds + bufo + brow + 1*1024 + (CH)); \
    b2 = *(const bf16x8*)(lds + bufo + brow + 2*1024 + (CH));  \
    b3 = *(const bf16x8*)(lds + bufo + brow + 3*1024 + (CH));
#define MFMA16(mq) \
    __builtin_amdgcn_s_setprio(1); \
    { const bf16x8 aa[4] = {a0,a1,a2,a3}; const bf16x8 bb4[4] = {b0,b1,b2,b3}; \
      _Pragma("unroll") for (int i_ = 0; i_ < 4; i_++) \
        _Pragma("unroll") for (int j_ = 0; j_ < 4; j_++) \
          acc[(mq)*4+i_][j_] = MM(aa[i_], bb4[j_], acc[(mq)*4+i_][j_]); } \
    __builtin_amdgcn_s_setprio(0);

  { const int nb = 0; const long nc = 0;
    STG_B(0); STG_B(1); STG_B(2); STG_B(3);
    STG_A(0); STG_A(1); STG_A(2); STG_A(3);
  }
  asm volatile("s_waitcnt vmcnt(0)" ::: "memory");
  BAR();

  int bufo = 0;
  for (int tt = 0; tt < NT; ++tt){
    const int nb = bufo ^ 32768;
    const bool st = (tt + 1 < NT);
    const long nc = (long)(tt + 1) * 64;
    bf16x8 a0,a1,a2,a3,b0,b1,b2,b3;
    LOADF(0, chk0);
    if (st){ STG_B(0); STG_B(1); STG_B(2); STG_B(3); }
    BAR();
    MFMA16(0);
    BAR();
    LOADF(0, chk1);
    if (st){ STG_A(0); STG_A(1); STG_A(2); STG_A(3); }
    BAR();
    MFMA16(0);
    BAR();
    LOADF(1, chk0);
    BAR();
    MFMA16(1);
    BAR();
    LOADF(1, chk1);
    asm volatile("s_waitcnt vmcnt(0)" ::: "memory");
    BAR();
    MFMA16(1);
    BAR();
    bufo = nb;
  }
#undef STG_A
#undef STG_B
#undef LOADF
#undef MFMA16

  const int r4 = lg * 4;
  // pack bf16 C tile into LDS (chunk-XOR swizzled), then full-line stores
#pragma unroll
  for (int nf = 0; nf < 4; nf++){
    const int colt = wc*64 + nf*16 + lr;           // tile col 0..255
    const float bv = bias[n0 + colt];
#pragma unroll
    for (int mf = 0; mf < 8; mf++){
      const int rowt = wr*128 + mf*16 + r4;
#pragma unroll
      for (int r = 0; r < 4; r++){
        float v = acc[mf][nf][r] + bv;
        if (EPI == 1) v = fmaxf(v, 0.f);
        const int row = rowt + r;
        lds[row*256 + (((colt >> 3) ^ (row & 7)) << 3) + (colt & 7)] = f2bf(v);
      }
    }
  }
  BAR();
  u16* cbase = (u16*)Cout + n0;
#pragma unroll
  for (int pass = 0; pass < 2; pass++){
#pragma unroll
    for (int it = 0; it < 8; it++){
      const int row = it*32 + w*4 + (l >> 4);
      const int ck  = (l & 15) + pass*16;
      const uint4 v = *(const uint4*)(lds + row*256 + ((ck ^ (row & 7)) << 3));
      *(uint4*)(cbase + (m0 + row) * (long)N + ck*8) = v;
    }
  }
}

// =============== 128x128 GEMM: 4 waves x 64x64, BK=32, 4 blocks/CU ==============
// 2:1 MFMA:ds_read at 16 waves/CU. bf16 epilogue via LDS (32KB full-line stores).
template<int EPI>
__global__ __launch_bounds__(256, 4)
void k_gemm_n128(const u16* __restrict__ A, const u16* __restrict__ W,
                 const float* __restrict__ bias, void* __restrict__ Cout,
                 int N, int K){
  __shared__ u16 lds[16384];                 // 32 KiB: 2 bufs x (A 4096 + B 4096) u16
  const int t = threadIdx.x;
  const int w = t >> 6, l = t & 63;
  const int lr = l & 15, lg = l >> 4;
  const int wr = w >> 1, wc = w & 1;

  int lin = blockIdx.y * gridDim.x + blockIdx.x;
  const int nwg = gridDim.x * gridDim.y;
  lin = (lin & 7) * (nwg >> 3) + (lin >> 3);
  const long m0 = (long)(lin / gridDim.x) * 128;
  const long n0 = (long)(lin % gridDim.x) * 128;

  const int schk = (t & 3) ^ ((t >> 3) & 3);
  const u16* gA = A + (m0 + (t >> 2)) * (long)K + schk * 8;
  const u16* gB = W + (n0 + (t >> 2)) * (long)K + schk * 8;

  const int ch = (lg ^ ((lr >> 1) & 3)) * 8;
  const int aoff = wr*2048 + lr*32 + ch;          // + mf*512
  const int boff = 4096 + wc*2048 + lr*32 + ch;   // + nf*512

  f32x4 acc[4][4] = {};
  const int NT = K >> 5;

#define STG128(nb, nc) \
    gld_lds16(gA + (nc),              (void*)(lds + (nb) + 0    + w*512)); \
    gld_lds16(gA + 64*(long)K + (nc), (void*)(lds + (nb) + 2048 + w*512)); \
    gld_lds16(gB + (nc),              (void*)(lds + (nb) + 4096 + w*512)); \
    gld_lds16(gB + 64*(long)K + (nc), (void*)(lds + (nb) + 6144 + w*512));

  STG128(0, 0);
  asm volatile("s_waitcnt vmcnt(0)" ::: "memory");
  BAR();

  int bufo = 0;
  for (int tt = 0; tt < NT; ++tt){
    const int nb = bufo ^ 8192;
    const bool st = (tt + 1 < NT);
    const long nc = (long)(tt + 1) * 32;
    if (st){ STG128(nb, nc); }
    bf16x8 a0,a1,a2,a3,b0,b1,b2,b3;
    a0 = *(const bf16x8*)(lds + bufo + aoff + 0*512);
    a1 = *(const bf16x8*)(lds + bufo + aoff + 1*512);
    a2 = *(const bf16x8*)(lds + bufo + aoff + 2*512);
    a3 = *(const bf16x8*)(lds + bufo + aoff + 3*512);
    b0 = *(const bf16x8*)(lds + bufo + boff + 0*512);
    b1 = *(const bf16x8*)(lds + bufo + boff + 1*512);
    b2 = *(const bf16x8*)(lds + bufo + boff + 2*512);
    b3 = *(const bf16x8*)(lds + bufo + boff + 3*512);
    __builtin_amdgcn_s_setprio(1);
    acc[0][0] = MM(a0,b0,acc[0][0]); acc[0][1] = MM(a0,b1,acc[0][1]);
    acc[0][2] = MM(a0,b2,acc[0][2]); acc[0][3] = MM(a0,b3,acc[0][3]);
    acc[1][0] = MM(a1,b0,acc[1][0]); acc[1][1] = MM(a1,b1,acc[1][1]);
    acc[1][2] = MM(a1,b2,acc[1][2]); acc[1][3] = MM(a1,b3,acc[1][3]);
    acc[2][0] = MM(a2,b0,acc[2][0]); acc[2][1] = MM(a2,b1,acc[2][1]);
    acc[2][2] = MM(a2,b2,acc[2][2]); acc[2][3] = MM(a2,b3,acc[2][3]);
    acc[3][0] = MM(a3,b0,acc[3][0]); acc[3][1] = MM(a3,b1,acc[3][1]);
    acc[3][2] = MM(a3,b2,acc[3][2]); acc[3][3] = MM(a3,b3,acc[3][3]);
    __builtin_amdgcn_s_setprio(0);
    if (st) asm volatile("s_waitcnt vmcnt(0)" ::: "memory");
    BAR();
    bufo = nb;
  }
#undef STG128

  const int r4 = lg * 4;
#pragma unroll
  for (int nf = 0; nf < 4; nf++){
    const int colt = wc*64 + nf*16 + lr;           // tile col 0..127
    const float bv = bias[n0 + colt];
#pragma unroll
    for (int mf = 0; mf < 4; mf++){
      const int rowt = wr*64 + mf*16 + r4;
#pragma unroll
      for (int r = 0; r < 4; r++){
        float v = acc[mf][nf][r] + bv;
        if (EPI == 1) v = fmaxf(v, 0.f);
        const int row = rowt + r;
        lds[row*128 + (((colt >> 3) ^ (row & 7)) << 3) + (colt & 7)] = f2bf(v);
      }
    }
  }
  BAR();
  u16* cbase = (u16*)Cout + n0;
#pragma unroll
  for (int it = 0; it < 8; it++){
    const int row = it*16 + w*4 + (l >> 4);
    const int ck  = l & 15;
    const uint4 v = *(const uint4*)(lds + row*128 + ((ck ^ (row & 7)) << 3));
    *(uint4*)(cbase + (m0 + row) * (long)N + ck*8) = v;
  }
}

// =============== input projection GEMM: h = x(Mx64) * W_in(1024x64)^T + b + pe ==
__global__ __launch_bounds__(256)
void k_gemm_in(const u16* __restrict__ A, const u16* __restrict__ W,
               const float* __restrict__ bias, const float* __restrict__ pe,
               float* __restrict__ hf, u16* __restrict__ hbf, u16* __restrict__ xad){
  __shared__ u16 sA[128*64];
  __shared__ u16 sB[128*64];
  const int t = threadIdx.x;
  const int w = t >> 6, l = t & 63;
  const int lr = l & 15, lg = l >> 4;
  const long m0 = (long)blockIdx.y * 128;
  const long n0 = (long)blockIdx.x * 128;
  const int wm = (w >> 1) << 6, wn = (w & 1) << 6;
  const int srow = t >> 3;                   // 0..31 per issue
  const int schk = (t & 7) ^ (srow & 7);
  const u16* gA = A + (m0 + srow) * 64 + schk * 8;
  const u16* gB = W + (n0 + srow) * 64 + schk * 8;
#pragma unroll
  for (int i = 0; i < 4; i++){
    gld_lds16(gA + i*32*64, (void*)(sA + i*2048 + (t>>6)*512));
    gld_lds16(gB + i*32*64, (void*)(sB + i*2048 + (t>>6)*512));
  }
  asm volatile("s_waitcnt vmcnt(0)" ::: "memory");
  __syncthreads();
  f32x4 acc[4][4] = {};
#pragma unroll
  for (int kk = 0; kk < 2; kk++){
    bf16x8 af[4], bfv[4];
#pragma unroll
    for (int i = 0; i < 4; i++){
      const int row = wm + i*16 + lr;
      af[i] = *(const bf16x8*)(sA + row*64 + ((kk*4+lg)^(row&7))*8);
    }
#pragma unroll
    for (int j = 0; j < 4; j++){
      const int row = wn + j*16 + lr;
      bfv[j] = *(const bf16x8*)(sB + row*64 + ((kk*4+lg)^(row&7))*8);
    }
#pragma unroll
    for (int i = 0; i < 4; i++)
#pragma unroll
      for (int j = 0; j < 4; j++)
        acc[i][j] = MM(af[i], bfv[j], acc[i][j]);
  }
  const int r0 = lg * 4;
#pragma unroll
  for (int j = 0; j < 4; j++){
    const long col = n0 + wn + j*16 + lr;
    const float bv = bias[col];
#pragma unroll
    for (int i = 0; i < 4; i++){
      const long row = m0 + wm + i*16 + r0;
#pragma unroll
      for (int r = 0; r < 4; r++){
        const long rr = row + r;
        if (rr >= MTOK) continue;
        const float v = acc[i][j][r] + bv + pe[(rr % 25)*1024 + col];
        const u16 hv = f2bf(v);
        hf[rr*1024 + col] = v;
        hbf[rr*1024 + col] = hv;
        const long bq = rr / 600, tq = rr % 600;
        xad[((bq*TP1 + 1 + tq) << 10) + col] = hv;
      }
    }
  }
}

// =============== out-projection GEMM: M=9600, N=128(52 valid), K=1024 ==========
__global__ __launch_bounds__(256)
void k_gemm_out(const u16* __restrict__ A, const u16* __restrict__ W,
                const float* __restrict__ bias, float* __restrict__ outp){
  __shared__ u16 sA[128*32];
  __shared__ u16 sB[128*32];
  const int t = threadIdx.x;
  const int w = t >> 6, l = t & 63;
  const long m0 = (long)blockIdx.y * 128;
  const int wm = (w >> 1) << 6, wn = (w & 1) << 6;
  const int K = 1024;
  f32x4 acc[4][4] = {};
  const char* gA0 = (const char*)(A + (m0 + (t >> 2)) * (long)K) + (t & 3) * 16;
  const char* gA1 = gA0 + 64 * (long)K * 2;
  const char* gB0 = (const char*)(W + (long)(t >> 2) * K) + (t & 3) * 16;
  const char* gB1 = gB0 + 64 * (long)K * 2;
  char* lA = (char*)sA + w * 1024;
  char* lB = (char*)sB + w * 1024;
  const int lr = l & 15;
  const int lkb = (l >> 4) * 16;
  for (long k0 = 0; k0 < K; k0 += 32){
    const long kb = k0 * 2;
    gld_lds16(gA0 + kb, lA);
    gld_lds16(gA1 + kb, lA + 4096);
    gld_lds16(gB0 + kb, lB);
    gld_lds16(gB1 + kb, lB + 4096);
    __syncthreads();
    bf16x8 af[4], bfv[4];
#pragma unroll
    for (int i = 0; i < 4; i++)
      af[i] = *(const bf16x8*)((const char*)sA + (wm + i*16 + lr)*64 + lkb);
#pragma unroll
    for (int j = 0; j < 4; j++)
      bfv[j] = *(const bf16x8*)((const char*)sB + (wn + j*16 + lr)*64 + lkb);
#pragma unroll
    for (int i = 0; i < 4; i++)
#pragma unroll
      for (int j = 0; j < 4; j++)
        acc[i][j] = MM(af[i], bfv[j], acc[i][j]);
    __syncthreads();
  }
  const int r0 = (l >> 4) * 4;
#pragma unroll
  for (int j = 0; j < 4; j++){
    const int col = wn + j*16 + lr;
    if (col >= IN_) continue;
    const float bv = bias[col];
#pragma unroll
    for (int i = 0; i < 4; i++){
      const long row = m0 + wm + i*16 + r0;
#pragma unroll
      for (int r = 0; r < 4; r++)
        outp[(row + r) * (long)IN_ + col] = acc[i][j][r] + bv;
    }
  }
}

// ---------------- V transpose: qkv V-part -> vt[b][h][d(128)][VTK keys] ---------
__global__ __launch_bounds__(256)
void k_vtrans(const u16* __restrict__ qkv, u16* __restrict__ vt){
  const int b = blockIdx.z;
  const int h = blockIdx.y >> 1;
  const int d0 = (blockIdx.y & 1) * 64;
  const int k0 = blockIdx.x * 64;
  __shared__ u16 tile[64][72];
  const int t = threadIdx.x;
#pragma unroll
  for (int it = 0; it < 2; it++){
    const int idx = t + it*256;
    const int kk = idx >> 3;
    const int dd = (idx & 7) * 8;
    const int kabs = k0 + kk;
    union { bf16x8 v; u16 us[8]; } u;
    if (kabs <= 600)
      u.v = *(const bf16x8*)(qkv + ((long)b*TP1 + kabs)*3072 + 2048 + h*128 + d0 + dd);
    else {
#pragma unroll
      for (int j = 0; j < 8; j++) u.us[j] = 0;
    }
    *(bf16x8*)(&tile[kk][dd]) = u.v;
  }
  __syncthreads();
#pragma unroll
  for (int it = 0; it < 2; it++){
    const int idx = t + it*256;
    const int dd = idx >> 3;
    const int kc = (idx & 7) * 8;
    if (k0 + kc + 7 < VTK){
      union { uint4 o; u16 us[8]; } u;
#pragma unroll
      for (int j = 0; j < 8; j++) u.us[j] = tile[kc + j][dd];
      *(uint4*)(vt + ((long)(b*8 + h)*128 + d0 + dd)*VTK + k0 + kc) = u.o;
    }
  }
}

// ---------------- build fp32 bias table [8][640][608] from alibi input ----------
// col 0 = 0 (adapter), cols 1..600 = alibi[h][q][j], cols 601..607 = -1e30,
// rows 600..639 = 0 (pad for discarded q rows).
__global__ void k_build_bias(const float* __restrict__ alibi, float* __restrict__ bt){
  const int h = blockIdx.y;
  const int tq = blockIdx.x;                 // 0..639
  float* dst = bt + ((long)(h*640 + tq))*608;
  const float* src = alibi + ((long)h*600 + tq)*600;
  for (int c = threadIdx.x; c < 608; c += 256){
    float v;
    if (tq >= 600)      v = 0.f;
    else if (c == 0)    v = 0.f;
    else if (c <= 600)  v = src[c-1];
    else                v = -1e30f;
    dst[c] = v;
  }
}

// ---------------- self-attention v4: bias-table softmax (1 fma per key) ---------
__global__ __launch_bounds__(256)
void k_sa_attn3(const u16* __restrict__ qkv, const u16* __restrict__ vt,
                const float* __restrict__ bias_t, u16* __restrict__ outp){
  const int id = blockIdx.x;
  const int g  = id & 127;
  const int qt = id >> 7;
  const int b = g >> 3, h = g & 7;
  const int w = threadIdx.x >> 6, l = threadIdx.x & 63;
  const int lr = l & 15, lg = l >> 4;
  const int q0 = qt * 64 + w * 16;
  const float scale = 0.08838834764831845f;

  __shared__ u16 Kl[2][4096];
  __shared__ u16 Vl[2][4096];
  __shared__ u16 Pl[4][16*40];
  __shared__ float cS[4][16];
  __shared__ float iS[4][16];

  const long bb = (long)b * TP1;
  const u16* qptr = qkv + (bb + 1 + q0 + lr) * 3072 + h * 128 + lg * 8;
  bf16x8 aq[4];
#pragma unroll
  for (int kk = 0; kk < 4; kk++) aq[kk] = *(const bf16x8*)(qptr + kk * 32);

  const int kj0 = w*2, kj1 = w*2 + 1;
  const int kkey0 = kj0*4 + (l >> 4), kkey1 = kj1*4 + (l >> 4);
  const u16* kg0 = qkv + (bb + kkey0)*3072 + 1024 + h*128 + (((l&15) ^ (kkey0&7)))*8;
  const u16* kg1 = qkv + (bb + kkey1)*3072 + 1024 + h*128 + (((l&15) ^ (kkey1&7)))*8;
  const u16* vbase = vt + (long)(b*8 + h) * 128 * VTK;
  const int vd0 = kj0*16 + (l >> 2), vd1 = kj1*16 + (l >> 2);
  const u16* vg0 = vbase + (long)vd0*VTK + ((l&3) ^ ((vd0 >> 1) & 3))*8;
  const u16* vg1 = vbase + (long)vd1*VTK + ((l&3) ^ ((vd1 >> 1) & 3))*8;

  // bias rows for this wave's 16 q rows; lane reads row lg*4+r, col kb0+{lr,16+lr}
  const float* brow0 = bias_t + ((long)(h*640 + q0 + lg*4))*608 + lr;

#define STAGE(buf, kb) \
  gld_lds16(kg0 + (long)(kb)*3072, (void*)(Kl[buf] + kj0*512)); \
  gld_lds16(kg1 + (long)(kb)*3072, (void*)(Kl[buf] + kj1*512)); \
  gld_lds16(vg0 + (kb),            (void*)(Vl[buf] + kj0*512)); \
  gld_lds16(vg1 + (kb),            (void*)(Vl[buf] + kj1*512));

  f32x4 o[8] = {};
  float mrow[4] = {-1e30f, -1e30f, -1e30f, -1e30f};
  float lsum[4] = {0.f, 0.f, 0.f, 0.f};

  STAGE(0, 0);
  asm volatile("s_waitcnt vmcnt(0)" ::: "memory");
  BAR();

  for (int kt = 0; kt < 19; kt++){
    const int kb0 = kt * 32;
    const int cur = kt & 1;
    const bool st = (kt < 18);
    if (st){ STAGE(cur ^ 1, kb0 + 32); }
    f32x4 s0 = {}, s1 = {};
#pragma unroll
    for (int kk = 0; kk < 4; kk++){
      const int sw = ((kk*4 + lg) ^ (lr & 7)) * 8;
      bf16x8 bk0 = *(const bf16x8*)(Kl[cur] + lr*128 + sw);
      bf16x8 bk1 = *(const bf16x8*)(Kl[cur] + (lr+16)*128 + sw);
      s0 = MM(aq[kk], bk0, s0);
      s1 = MM(aq[kk], bk1, s1);
    }
#pragma unroll
    for (int r = 0; r < 4; r++){
      const float* br = brow0 + r*608 + kb0;
      const float v0 = fmaf(s0[r], scale, br[0]);
      const float v1 = fmaf(s1[r], scale, br[16]);
      float mx = fmaxf(v0, v1);
#pragma unroll
      for (int d = 8; d >= 1; d >>= 1) mx = fmaxf(mx, __shfl_xor(mx, d, 64));
      const float mnew = fmaxf(mrow[r], mx);
      const float corr = __expf(mrow[r] - mnew);
      const float p0 = __expf(v0 - mnew);
      const float p1 = __expf(v1 - mnew);
      float rs = p0 + p1;
#pragma unroll
      for (int d = 8; d >= 1; d >>= 1) rs += __shfl_xor(rs, d, 64);
      lsum[r] = lsum[r] * corr + rs;
      mrow[r] = mnew;
      if (lr == 0) cS[w][lg*4 + r] = corr;
      Pl[w][(lg*4 + r)*40 + lr]      = f2bf(p0);
      Pl[w][(lg*4 + r)*40 + 16 + lr] = f2bf(p1);
    }
    const float c = cS[w][lr];
    const bool resc = __any(c != 1.0f);
    const bf16x8 pa = *(const bf16x8*)(&Pl[w][lr*40 + lg*8]);
#pragma unroll
    for (int dc = 0; dc < 8; dc++){
      const int d = dc*16 + lr;
      const bf16x8 va = *(const bf16x8*)(Vl[cur] + d*32 + ((lg ^ ((d >> 1) & 3))*8));
      if (resc){
#pragma unroll
        for (int rr = 0; rr < 4; rr++) o[dc][rr] *= c;
      }
      o[dc] = MM(va, pa, o[dc]);
    }
    if (st){
      asm volatile("s_waitcnt vmcnt(0)" ::: "memory");
      BAR();
    }
  }
#undef STAGE
#pragma unroll
  for (int r = 0; r < 4; r++)
    if (lr == 0) iS[w][lg*4 + r] = 1.f / lsum[r];
  const int tq = q0 + lr;
  if (tq < 600){
    const float inv = iS[w][lr];
    u16* op = outp + ((long)b*600 + tq) * 1024 + h * 128;
#pragma unroll
    for (int dc = 0; dc < 8; dc++){
      union { uint2 o8; u16 us[4]; } pk;
#pragma unroll
      for (int rr = 0; rr < 4; rr++) pk.us[rr] = f2bf(o[dc][rr] * inv);
      *(uint2*)(op + dc*16 + lg*4) = pk.o8;
    }
  }
}

// ---------------- cross-attention: exact 2-key softmax ---------------------------
__global__ __launch_bounds__(256)
void k_ca_attn(const u16* __restrict__ qca, const u16* __restrict__ kv,
               u16* __restrict__ outp){
  const int wid = blockIdx.x * 4 + (threadIdx.x >> 6);
  const int l = threadIdx.x & 63;
  if (wid >= MTOK) return;
  const int b = wid / 600, t = wid % 600;
  const u16* q  = qca + (long)wid * 1024;
  const u16* ka = kv + ((long)b * TP1) * 2048;
  const u16* km = kv + ((long)(b * TP1 + 1 + t)) * 2048;
  const float scale = 0.08838834764831845f;
#pragma unroll
  for (int h = 0; h < 8; h++){
    const int d = h*128 + l*2;
    const float q0 = bf2f(q[d]),  q1 = bf2f(q[d+1]);
    float s0 = q0*bf2f(ka[d]) + q1*bf2f(ka[d+1]);
    float s1 = q0*bf2f(km[d]) + q1*bf2f(km[d+1]);
#pragma unroll
    for (int dd = 32; dd >= 1; dd >>= 1){
      s0 += __shfl_xor(s0, dd, 64);
      s1 += __shfl_xor(s1, dd, 64);
    }
    s0 *= scale; s1 *= scale;
    const float mx = fmaxf(s0, s1);
    const float e0 = __expf(s0 - mx), e1 = __expf(s1 - mx);
    const float inv = 1.f / (e0 + e1);
    const float o0 = (e0*bf2f(ka[1024+d])   + e1*bf2f(km[1024+d]))   * inv;
    const float o1 = (e0*bf2f(ka[1024+d+1]) + e1*bf2f(km[1024+d+1])) * inv;
    const unsigned pack = (unsigned)f2bf(o0) | ((unsigned)f2bf(o1) << 16);
    *(unsigned*)(outp + (long)wid*1024 + d) = pack;
  }
}

// ------- residual-add + in-place LayerNorm (float4); optional xadpt mirror -------
__global__ __launch_bounds__(256)
void k_ln2(float* __restrict__ hf, const u16* __restrict__ sub,
           const float* __restrict__ g, const float* __restrict__ bb,
           u16* __restrict__ hbf, u16* __restrict__ xad){
  const long m = blockIdx.x;
  const int t = threadIdx.x;
  float4* r = (float4*)(hf + m*1024);
  float4 v = r[t];
  union { uint2 u; u16 us[4]; } sv;
  sv.u = *(const uint2*)(sub + m*1024 + t*4);
  v.x += bf2f(sv.us[0]); v.y += bf2f(sv.us[1]);
  v.z += bf2f(sv.us[2]); v.w += bf2f(sv.us[3]);
  float sum = v.x + v.y + v.z + v.w;
  float sumsq = v.x*v.x + v.y*v.y + v.z*v.z + v.w*v.w;
#pragma unroll
  for (int d = 32; d >= 1; d >>= 1){ sum += __shfl_xor(sum,d,64); sumsq += __shfl_xor(sumsq,d,64); }
  __shared__ float red[8];
  const int w = t >> 6;
  if ((t & 63) == 0){ red[w] = sum; red[4+w] = sumsq; }
  __syncthreads();
  sum   = red[0]+red[1]+red[2]+red[3];
  sumsq = red[4]+red[5]+red[6]+red[7];
  const float mu  = sum * (1.f/1024.f);
  const float var = sumsq * (1.f/1024.f) - mu*mu;
  const float rstd = rsqrtf(var + 1e-5f);
  const float4 gv = ((const float4*)g)[t];
  const float4 bv = ((const float4*)bb)[t];
  float4 y;
  y.x = (v.x - mu) * rstd * gv.x + bv.x;
  y.y = (v.y - mu) * rstd * gv.y + bv.y;
  y.z = (v.z - mu) * rstd * gv.z + bv.z;
  y.w = (v.w - mu) * rstd * gv.w + bv.w;
  r[t] = y;
  union { uint2 u; u16 us[4]; } p;
  p.us[0] = f2bf(y.x); p.us[1] = f2bf(y.y); p.us[2] = f2bf(y.z); p.us[3] = f2bf(y.w);
  *(uint2*)(hbf + m*1024 + t*4) = p.u;
  if (xad){
    const long bq = m / 600, tq = m % 600;
    *(uint2*)(xad + ((bq*TP1 + 1 + tq) << 10) + t*4) = p.u;
  }
}

// ---------------- small fp32 kernels ---------------------------------------------
__global__ void k_temb_sin(const int* __restrict__ ts, float* __restrict__ emb){
  const int b = blockIdx.x;
  const float t = (float)ts[b];
  for (int j = threadIdx.x; j < 1024; j += 256){
    const int jj = j < 512 ? j : j - 512;
    const float ex = expf(-9.210340371976184f * (float)jj / 511.0f);
    const float v = t * ex;
    emb[b*1024 + j] = (j < 512) ? sinf(v) : cosf(v);
  }
}

__global__ void k_te_mm(const float* __restrict__ in, const float* __restrict__ W,
                        const float* __restrict__ bv, float* __restrict__ outp,
                        int act, u16* __restrict__ xad, u16* __restrict__ mad){
  __shared__ float row[1024];
  const int b = blockIdx.y;
  for (int k = threadIdx.x; k < 1024; k += 256) row[k] = in[b*1024 + k];
  __syncthreads();
  const int n = blockIdx.x*256 + threadIdx.x;
  const float* wr = W + (long)n*1024;
  float s = 0.f;
  for (int k = 0; k < 1024; k += 4){
    const float4 w4 = *(const float4*)(wr + k);
    s += row[k]*w4.x + row[k+1]*w4.y + row[k+2]*w4.z + row[k+3]*w4.w;
  }
  s += bv[n];
  if (act) s = s / (1.f + expf(-s));   // silu
  outp[b*1024 + n] = s;
  if (xad){
    const u16 h = f2bf(s);
    xad[((long)b*TP1)*1024 + n] = h;
    mad[((long)b*TP1)*1024 + n] = h;
  }
}

// ---------------- data movement / conversion -------------------------------------
__global__ void k_convert_weights(const float* __restrict__ sqkv, const float* __restrict__ swo,
                                  const float* __restrict__ cqkv, const float* __restrict__ cwo,
                                  const float* __restrict__ fw1,  const float* __restrict__ fw2,
                                  u16* __restrict__ wbuf){
  const long idx = ((long)blockIdx.x*256 + threadIdx.x) * 8;
  const float* src; long off;
  if      (idx <  3145728L){ src = sqkv; off = idx; }
  else if (idx <  4194304L){ src = swo;  off = idx -  3145728L; }
  else if (idx <  7340032L){ src = cqkv; off = idx -  4194304L; }
  else if (idx <  8388608L){ src = cwo;  off = idx -  7340032L; }
  else if (idx < 12582912L){ src = fw1;  off = idx -  8388608L; }
  else                     { src = fw2;  off = idx - 12582912L; }
  const float4 a = *(const float4*)(src + off);
  const float4 c = *(const float4*)(src + off + 4);
  uint4 o;
  o.x = (unsigned)f2bf(a.x) | ((unsigned)f2bf(a.y) << 16);
  o.y = (unsigned)f2bf(a.z) | ((unsigned)f2bf(a.w) << 16);
  o.z = (unsigned)f2bf(c.x) | ((unsigned)f2bf(c.y) << 16);
  o.w = (unsigned)f2bf(c.z) | ((unsigned)f2bf(c.w) << 16);
  *(uint4*)(wbuf + idx) = o;
}

__global__ void k_convert_wout(const float* __restrict__ src, u16* __restrict__ dst){
  const int i = blockIdx.x*256 + threadIdx.x;   // 131072 total
  const int row = i >> 10;
  dst[i] = (row < IN_) ? f2bf(src[i]) : (u16)0;
}

__global__ void k_convert_x(const float* __restrict__ x, u16* __restrict__ dst){
  const int i = blockIdx.x*256 + threadIdx.x;   // MPAD*64 = 622592
  const int row = i >> 6, c = i & 63;
  float v = 0.f;
  if (row < MTOK && c < IN_) v = x[(long)row*IN_ + c];
  dst[i] = f2bf(v);
}

__global__ void k_convert_win(const float* __restrict__ wi, u16* __restrict__ dst){
  const int i = blockIdx.x*256 + threadIdx.x;   // 1024*64 = 65536
  const int row = i >> 6, c = i & 63;
  dst[i] = (c < IN_) ? f2bf(wi[(long)row*IN_ + c]) : (u16)0;
}

__global__ void k_build_memadpt(const float* __restrict__ mem, u16* __restrict__ mad){
  const long i = ((long)blockIdx.x*256 + threadIdx.x) * 8;
  const long tok = i >> 10, col = i & 1023;
  const long b = tok / 600, s = tok % 600;
  const float4 a = *(const float4*)(mem + i);
  const float4 c = *(const float4*)(mem + i + 4);
  uint4 o;
  o.x = (unsigned)f2bf(a.x) | ((unsigned)f2bf(a.y) << 16);
  o.y = (unsigned)f2bf(a.z) | ((unsigned)f2bf(a.w) << 16);
  o.z = (unsigned)f2bf(c.x) | ((unsigned)f2bf(c.y) << 16);
  o.w = (unsigned)f2bf(c.z) | ((unsigned)f2bf(c.w) << 16);
  *(uint4*)(mad + ((b*TP1 + 1 + s) << 10) + col) = o;
}

// ---------------- host-side launch -----------------------------------------------
extern "C" void kernel_launch(void* const* d_in, const int* in_sizes, int n_in,
                              void* d_out, int out_size, void* d_ws, size_t ws_size,
                              hipStream_t stream){
  const float* x        = (const float*)d_in[0];
  const float* memory   = (const float*)d_in[1];
  const int*   tsteps   = (const int*)  d_in[2];
  const float* pe       = (const float*)d_in[3];
  const float* alibi    = (const float*)d_in[4];
  const float* W_in     = (const float*)d_in[5];
  const float* b_in     = (const float*)d_in[6];
  const float* te_W1    = (const float*)d_in[7];
  const float* te_b1    = (const float*)d_in[8];
  const float* te_W2    = (const float*)d_in[9];
  const float* te_b2    = (const float*)d_in[10];
  const float* sa_Wqkv  = (const float*)d_in[11];
  const float* sa_bqkv  = (const float*)d_in[12];
  const float* sa_Wo    = (const float*)d_in[13];
  const float* sa_bo    = (const float*)d_in[14];
  const float* ca_Wqkv  = (const float*)d_in[15];
  const float* ca_bqkv  = (const float*)d_in[16];
  const float* ca_Wo    = (const float*)d_in[17];
  const float* ca_bo    = (const float*)d_in[18];
  const float* ff_W1    = (const float*)d_in[19];
  const float* ff_b1    = (const float*)d_in[20];
  const float* ff_W2    = (const float*)d_in[21];
  const float* ff_b2    = (const float*)d_in[22];
  const float* ln1_g    = (const float*)d_in[23];
  const float* ln2_g    = (const float*)d_in[24];
  const float* ln3_g    = (const float*)d_in[25];
  const float* ln1_b    = (const float*)d_in[26];
  const float* ln2_b    = (const float*)d_in[27];
  const float* ln3_b    = (const float*)d_in[28];
  const float* W_out    = (const float*)d_in[29];
  const float* b_out    = (const float*)d_in[30];

  char* ws = (char*)d_ws;   // ~324 MB used
  float* h_f    = (float*)(ws + 0);            //  9600x1024 f32
  u16*   h_bf   = (u16*)  (ws + 39321600);     //  9600x1024 bf16
  u16*   attn_bf= (u16*)  (ws + 58982400);     //  9600x1024
  u16*   xadpt  = (u16*)  (ws + 78643200);     //  9616x1024
  u16*   madpt  = (u16*)  (ws + 98336768);     //  9616x1024
  u16*   qkv    = (u16*)  (ws + 118030336);    //  MPADx3072
  u16*   ffb    = (u16*)  (ws + 177799168);    //  MPADx4096
  u16*   wbuf   = (u16*)  (ws + 257490944);    //  16.7M bf16
  u16*   sub_bf = (u16*)  (ws + 291045376);    //  MPADx1024 bf16 (GEMM C for residual)
  float* bias_t = (float*)(ws + 310968320);    //  8x640x608 f32 = 12.45 MB
  float* temb_a = (float*)(ws + 177799168);    //  alias ffb (prologue only)
  float* temb_b = (float*)(ws + 177864704);
  u16*   vtg    = (u16*)  (ws + 177799168 + 262144); // alias ffb (dead before FF1)
  u16*   x_bf   = wbuf;                        //  alias wbuf (prologue only) MPADx64
  u16*   win_bf = wbuf + 622592;               //  1024x64
  u16*   wout_bf= wbuf;                        //  reuse after layer loop

  u16* qca  = qkv;                             // 9600x1024 (token-major)
  u16* kvca = qkv + (long)MPAD * 1024;         // MPADx2048 (adapter-major)

  // time-embed + adapter + input projection (MFMA path) + bias table
  k_temb_sin<<<dim3(16), dim3(256), 0, stream>>>(tsteps, temb_a);
  k_te_mm<<<dim3(4,16), dim3(256), 0, stream>>>(temb_a, te_W1, te_b1, temb_b, 1, (u16*)nullptr, (u16*)nullptr);
  k_te_mm<<<dim3(4,16), dim3(256), 0, stream>>>(temb_b, te_W2, te_b2, temb_a, 0, xadpt, madpt);
  k_build_memadpt<<<dim3(4800), dim3(256), 0, stream>>>(memory, madpt);
  k_build_bias<<<dim3(640,8), dim3(256), 0, stream>>>(alibi, bias_t);
  k_convert_x<<<dim3(2432), dim3(256), 0, stream>>>(x, x_bf);
  k_convert_win<<<dim3(256), dim3(256), 0, stream>>>(W_in, win_bf);
  k_gemm_in<<<dim3(8,76), dim3(256), 0, stream>>>(x_bf, win_bf, b_in, pe, h_f, h_bf, xadpt);

  for (int l = 0; l < L_; l++){
    k_convert_weights<<<dim3(8192), dim3(256), 0, stream>>>(
        sa_Wqkv + (long)l*3145728, sa_Wo + (long)l*1048576,
        ca_Wqkv + (long)l*3145728, ca_Wo + (long)l*1048576,
        ff_W1 + (long)l*4194304,  ff_W2 + (long)l*4194304, wbuf);
    // --- self attention (xadpt maintained by k_gemm_in / ln3 of prev layer) ---
    k_gemm256<0><<<dim3(12,38), dim3(512), 0, stream>>>(xadpt, wbuf, sa_bqkv + l*3072, (void*)qkv, 3072, 1024);
    k_vtrans<<<dim3(10,16,16), dim3(256), 0, stream>>>(qkv, vtg);
    k_sa_attn3<<<dim3(1280), dim3(256), 0, stream>>>(qkv, vtg, bias_t, attn_bf);
    k_gemm_n128<0><<<dim3(8,76), dim3(256), 0, stream>>>(attn_bf, wbuf + 3145728, sa_bo + l*1024, (void*)sub_bf, 1024, 1024);
    k_ln2<<<dim3(9600), dim3(256), 0, stream>>>(h_f, sub_bf, ln1_g + l*1024, ln1_b + l*1024, h_bf, (u16*)nullptr);
    // --- cross attention (adapter + diagonal only) ---
    k_gemm_n128<0><<<dim3(8,76), dim3(256), 0, stream>>>(h_bf, wbuf + 4194304, ca_bqkv + l*3072, (void*)qca, 1024, 1024);
    k_gemm_n128<0><<<dim3(16,76), dim3(256), 0, stream>>>(madpt, wbuf + 4194304 + 1048576, ca_bqkv + l*3072 + 1024, (void*)kvca, 2048, 1024);
    k_ca_attn<<<dim3(2400), dim3(256), 0, stream>>>(qca, kvca, attn_bf);
    k_gemm_n128<0><<<dim3(8,76), dim3(256), 0, stream>>>(attn_bf, wbuf + 7340032, ca_bo + l*1024, (void*)sub_bf, 1024, 1024);
    k_ln2<<<dim3(9600), dim3(256), 0, stream>>>(h_f, sub_bf, ln2_g + l*1024, ln2_b + l*1024, h_bf, (u16*)nullptr);
    // --- feed forward ---
    k_gemm256<1><<<dim3(16,38), dim3(512), 0, stream>>>(h_bf, wbuf + 8388608, ff_b1 + l*4096, (void*)ffb, 4096, 1024);
    k_gemm_n128<0><<<dim3(8,76), dim3(256), 0, stream>>>(ffb, wbuf + 12582912, ff_b2 + l*1024, (void*)sub_bf, 1024, 4096);
    k_ln2<<<dim3(9600), dim3(256), 0, stream>>>(h_f, sub_bf, ln3_g + l*1024, ln3_b + l*1024, h_bf, xadpt);
  }
  k_convert_wout<<<dim3(512), dim3(256), 0, stream>>>(W_out, wout_bf);
  k_gemm_out<<<dim3(1,75), dim3(256), 0, stream>>>(h_bf, wout_bf, b_out, (float*)d_out);
}

// Round 17
// 5072.548 us; speedup vs baseline: 1.0833x; 1.0833x over previous
//
#include <hip/hip_runtime.h>
#include <stdint.h>

#define B_ 16
#define T_ 600
#define S_ 600
#define D_ 1024
#define H_ 8
#define HD_ 128
#define L_ 8
#define DFF_ 4096
#define IN_ 52
#define TP1 601
#define MTOK 9600   // B*T
#define MPAD 9728   // 38*256 padded rows
#define VTK 608     // padded key count for V^T

typedef unsigned short u16;
typedef float f32x4 __attribute__((ext_vector_type(4)));
typedef __bf16 bf16x8 __attribute__((ext_vector_type(8)));

__device__ __forceinline__ u16 f2bf(float f){
  union { float f; unsigned u; } v; v.f = f;
  v.u += 0x7FFFu + ((v.u >> 16) & 1u);
  return (u16)(v.u >> 16);
}
__device__ __forceinline__ float bf2f(u16 h){
  union { unsigned u; float f; } v; v.u = ((unsigned)h) << 16;
  return v.f;
}
__device__ __forceinline__ void gld_lds16(const void* g, void* l){
  __builtin_amdgcn_global_load_lds(
      (const __attribute__((address_space(1))) void*)(uintptr_t)g,
      (__attribute__((address_space(3))) void*)(uintptr_t)l, 16, 0, 0);
}
__device__ __forceinline__ f32x4 MM(bf16x8 a, bf16x8 b, f32x4 c){
  return __builtin_amdgcn_mfma_f32_16x16x32_bf16(a, b, c, 0, 0, 0);
}
#define BAR() asm volatile("s_barrier" ::: "memory")

// =============== 256x256 GEMM, BK=64, 8 waves, early-issue schedule ============
// EPI: 0 = bf16 out, 1 = relu+bf16. Epilogue: C tile packed to LDS (128KB) then
// full-line uint4 stores.
template<int EPI>
__global__ __launch_bounds__(512, 2)
void k_gemm256(const u16* __restrict__ A, const u16* __restrict__ W,
               const float* __restrict__ bias, void* __restrict__ Cout,
               int N, int K){
  __shared__ u16 lds[65536];                 // 128 KiB: 2 bufs x (A 16384 + B 16384) u16
  const int t = threadIdx.x;
  const int w = t >> 6, l = t & 63;
  const int lr = l & 15, lg = l >> 4;
  const int wr = w >> 2, wc = w & 3;

  int lin = blockIdx.y * gridDim.x + blockIdx.x;
  const int nwg = gridDim.x * gridDim.y;
  lin = (lin & 7) * (nwg >> 3) + (lin >> 3);
  const long m0 = (long)(lin / gridDim.x) * 256;
  const long n0 = (long)(lin % gridDim.x) * 256;

  const int srow = w*8 + (l >> 3);
  const int schk = (l & 7) ^ (l >> 3);
  const u16* gA = A + (m0 + srow) * (long)K + schk * 8;
  const u16* gB = W + (n0 + srow) * (long)K + schk * 8;

  const int chk0 = ((    lg) ^ (lr & 7)) * 8;
  const int chk1 = ((4 + lg) ^ (lr & 7)) * 8;
  const int arow = (wr*128 + lr) * 64;
  const int brow = (wc*64  + lr) * 64 + 16384;

  f32x4 acc[8][4] = {};
  const int NT = K >> 6;

#define STG_A(i) gld_lds16(gA + (long)(i)*64*K + nc, (void*)(lds + nb + (i)*4096 + w*512))
#define STG_B(i) gld_lds16(gB + (long)(i)*64*K + nc, (void*)(lds + nb + 16384 + (i)*4096 + w*512))
#define LOADF(mq, CH) \
    a0 = *(const bf16x8*)(lds + bufo + arow + ((mq)*4+0)*1024 + (CH)); \
    a1 = *(const bf16x8*)(lds + bufo + arow + ((mq)*4+1)*1024 + (CH)); \
    a2 = *(const bf16x8*)(lds + bufo + arow + ((mq)*4+2)*1024 + (CH)); \
    a3 = *(const bf16x8*)(lds + bufo + arow + ((mq)*4+3)*1024 + (CH)); \
    b0 = *(const bf16x8*)(lds + bufo + brow + 0*1024 + (CH)); \
    b1 = *(const bf16x8*)(lds + bufo + brow + 1*1024 + (CH)); \
    b2 = *(const bf16x8*)(lds + bufo + brow + 2*1024 + (CH));  \
    b3 = *(const bf16x8*)(lds + bufo + brow + 3*1024 + (CH));
#define MFMA16(mq) \
    __builtin_amdgcn_s_setprio(1); \
    { const bf16x8 aa[4] = {a0,a1,a2,a3}; const bf16x8 bb4[4] = {b0,b1,b2,b3}; \
      _Pragma("unroll") for (int i_ = 0; i_ < 4; i_++) \
        _Pragma("unroll") for (int j_ = 0; j_ < 4; j_++) \
          acc[(mq)*4+i_][j_] = MM(aa[i_], bb4[j_], acc[(mq)*4+i_][j_]); } \
    __builtin_amdgcn_s_setprio(0);

  { const int nb = 0; const long nc = 0;
    STG_B(0); STG_B(1); STG_B(2); STG_B(3);
    STG_A(0); STG_A(1); STG_A(2); STG_A(3);
  }
  asm volatile("s_waitcnt vmcnt(0)" ::: "memory");
  BAR();

  int bufo = 0;
  for (int tt = 0; tt < NT; ++tt){
    const int nb = bufo ^ 32768;
    const bool st = (tt + 1 < NT);
    const long nc = (long)(tt + 1) * 64;
    bf16x8 a0,a1,a2,a3,b0,b1,b2,b3;
    LOADF(0, chk0);
    if (st){ STG_B(0); STG_B(1); STG_B(2); STG_B(3); }
    BAR();
    MFMA16(0);
    BAR();
    LOADF(0, chk1);
    if (st){ STG_A(0); STG_A(1); STG_A(2); STG_A(3); }
    BAR();
    MFMA16(0);
    BAR();
    LOADF(1, chk0);
    BAR();
    MFMA16(1);
    BAR();
    LOADF(1, chk1);
    asm volatile("s_waitcnt vmcnt(0)" ::: "memory");
    BAR();
    MFMA16(1);
    BAR();
    bufo = nb;
  }
#undef STG_A
#undef STG_B
#undef LOADF
#undef MFMA16

  const int r4 = lg * 4;
  // pack bf16 C tile into LDS (chunk-XOR swizzled), then full-line stores
#pragma unroll
  for (int nf = 0; nf < 4; nf++){
    const int colt = wc*64 + nf*16 + lr;           // tile col 0..255
    const float bv = bias[n0 + colt];
#pragma unroll
    for (int mf = 0; mf < 8; mf++){
      const int rowt = wr*128 + mf*16 + r4;
#pragma unroll
      for (int r = 0; r < 4; r++){
        float v = acc[mf][nf][r] + bv;
        if (EPI == 1) v = fmaxf(v, 0.f);
        const int row = rowt + r;
        lds[row*256 + (((colt >> 3) ^ (row & 7)) << 3) + (colt & 7)] = f2bf(v);
      }
    }
  }
  BAR();
  u16* cbase = (u16*)Cout + n0;
#pragma unroll
  for (int pass = 0; pass < 2; pass++){
#pragma unroll
    for (int it = 0; it < 8; it++){
      const int row = it*32 + w*4 + (l >> 4);
      const int ck  = (l & 15) + pass*16;
      const uint4 v = *(const uint4*)(lds + row*256 + ((ck ^ (row & 7)) << 3));
      *(uint4*)(cbase + (m0 + row) * (long)N + ck*8) = v;
    }
  }
}

// =============== 128x128 GEMM: 4 waves x 64x64, BK=32, 4 blocks/CU ==============
// 2:1 MFMA:ds_read at 16 waves/CU. bf16 epilogue via LDS (32KB full-line stores).
template<int EPI>
__global__ __launch_bounds__(256, 4)
void k_gemm_n128(const u16* __restrict__ A, const u16* __restrict__ W,
                 const float* __restrict__ bias, void* __restrict__ Cout,
                 int N, int K){
  __shared__ u16 lds[16384];                 // 32 KiB: 2 bufs x (A 4096 + B 4096) u16
  const int t = threadIdx.x;
  const int w = t >> 6, l = t & 63;
  const int lr = l & 15, lg = l >> 4;
  const int wr = w >> 1, wc = w & 1;

  int lin = blockIdx.y * gridDim.x + blockIdx.x;
  const int nwg = gridDim.x * gridDim.y;
  lin = (lin & 7) * (nwg >> 3) + (lin >> 3);
  const long m0 = (long)(lin / gridDim.x) * 128;
  const long n0 = (long)(lin % gridDim.x) * 128;

  const int schk = (t & 3) ^ ((t >> 3) & 3);
  const u16* gA = A + (m0 + (t >> 2)) * (long)K + schk * 8;
  const u16* gB = W + (n0 + (t >> 2)) * (long)K + schk * 8;

  const int ch = (lg ^ ((lr >> 1) & 3)) * 8;
  const int aoff = wr*2048 + lr*32 + ch;          // + mf*512
  const int boff = 4096 + wc*2048 + lr*32 + ch;   // + nf*512

  f32x4 acc[4][4] = {};
  const int NT = K >> 5;

#define STG128(nb, nc) \
    gld_lds16(gA + (nc),              (void*)(lds + (nb) + 0    + w*512)); \
    gld_lds16(gA + 64*(long)K + (nc), (void*)(lds + (nb) + 2048 + w*512)); \
    gld_lds16(gB + (nc),              (void*)(lds + (nb) + 4096 + w*512)); \
    gld_lds16(gB + 64*(long)K + (nc), (void*)(lds + (nb) + 6144 + w*512));

  STG128(0, 0);
  asm volatile("s_waitcnt vmcnt(0)" ::: "memory");
  BAR();

  int bufo = 0;
  for (int tt = 0; tt < NT; ++tt){
    const int nb = bufo ^ 8192;
    const bool st = (tt + 1 < NT);
    const long nc = (long)(tt + 1) * 32;
    if (st){ STG128(nb, nc); }
    bf16x8 a0,a1,a2,a3,b0,b1,b2,b3;
    a0 = *(const bf16x8*)(lds + bufo + aoff + 0*512);
    a1 = *(const bf16x8*)(lds + bufo + aoff + 1*512);
    a2 = *(const bf16x8*)(lds + bufo + aoff + 2*512);
    a3 = *(const bf16x8*)(lds + bufo + aoff + 3*512);
    b0 = *(const bf16x8*)(lds + bufo + boff + 0*512);
    b1 = *(const bf16x8*)(lds + bufo + boff + 1*512);
    b2 = *(const bf16x8*)(lds + bufo + boff + 2*512);
    b3 = *(const bf16x8*)(lds + bufo + boff + 3*512);
    __builtin_amdgcn_s_setprio(1);
    acc[0][0] = MM(a0,b0,acc[0][0]); acc[0][1] = MM(a0,b1,acc[0][1]);
    acc[0][2] = MM(a0,b2,acc[0][2]); acc[0][3] = MM(a0,b3,acc[0][3]);
    acc[1][0] = MM(a1,b0,acc[1][0]); acc[1][1] = MM(a1,b1,acc[1][1]);
    acc[1][2] = MM(a1,b2,acc[1][2]); acc[1][3] = MM(a1,b3,acc[1][3]);
    acc[2][0] = MM(a2,b0,acc[2][0]); acc[2][1] = MM(a2,b1,acc[2][1]);
    acc[2][2] = MM(a2,b2,acc[2][2]); acc[2][3] = MM(a2,b3,acc[2][3]);
    acc[3][0] = MM(a3,b0,acc[3][0]); acc[3][1] = MM(a3,b1,acc[3][1]);
    acc[3][2] = MM(a3,b2,acc[3][2]); acc[3][3] = MM(a3,b3,acc[3][3]);
    __builtin_amdgcn_s_setprio(0);
    if (st) asm volatile("s_waitcnt vmcnt(0)" ::: "memory");
    BAR();
    bufo = nb;
  }
#undef STG128

  const int r4 = lg * 4;
#pragma unroll
  for (int nf = 0; nf < 4; nf++){
    const int colt = wc*64 + nf*16 + lr;           // tile col 0..127
    const float bv = bias[n0 + colt];
#pragma unroll
    for (int mf = 0; mf < 4; mf++){
      const int rowt = wr*64 + mf*16 + r4;
#pragma unroll
      for (int r = 0; r < 4; r++){
        float v = acc[mf][nf][r] + bv;
        if (EPI == 1) v = fmaxf(v, 0.f);
        const int row = rowt + r;
        lds[row*128 + (((colt >> 3) ^ (row & 7)) << 3) + (colt & 7)] = f2bf(v);
      }
    }
  }
  BAR();
  u16* cbase = (u16*)Cout + n0;
#pragma unroll
  for (int it = 0; it < 8; it++){
    const int row = it*16 + w*4 + (l >> 4);
    const int ck  = l & 15;
    const uint4 v = *(const uint4*)(lds + row*128 + ((ck ^ (row & 7)) << 3));
    *(uint4*)(cbase + (m0 + row) * (long)N + ck*8) = v;
  }
}

// =============== input projection GEMM: h = x(Mx64) * W_in(1024x64)^T + b + pe ==
__global__ __launch_bounds__(256)
void k_gemm_in(const u16* __restrict__ A, const u16* __restrict__ W,
               const float* __restrict__ bias, const float* __restrict__ pe,
               float* __restrict__ hf, u16* __restrict__ hbf, u16* __restrict__ xad){
  __shared__ u16 sA[128*64];
  __shared__ u16 sB[128*64];
  const int t = threadIdx.x;
  const int w = t >> 6, l = t & 63;
  const int lr = l & 15, lg = l >> 4;
  const long m0 = (long)blockIdx.y * 128;
  const long n0 = (long)blockIdx.x * 128;
  const int wm = (w >> 1) << 6, wn = (w & 1) << 6;
  const int srow = t >> 3;                   // 0..31 per issue
  const int schk = (t & 7) ^ (srow & 7);
  const u16* gA = A + (m0 + srow) * 64 + schk * 8;
  const u16* gB = W + (n0 + srow) * 64 + schk * 8;
#pragma unroll
  for (int i = 0; i < 4; i++){
    gld_lds16(gA + i*32*64, (void*)(sA + i*2048 + (t>>6)*512));
    gld_lds16(gB + i*32*64, (void*)(sB + i*2048 + (t>>6)*512));
  }
  asm volatile("s_waitcnt vmcnt(0)" ::: "memory");
  __syncthreads();
  f32x4 acc[4][4] = {};
#pragma unroll
  for (int kk = 0; kk < 2; kk++){
    bf16x8 af[4], bfv[4];
#pragma unroll
    for (int i = 0; i < 4; i++){
      const int row = wm + i*16 + lr;
      af[i] = *(const bf16x8*)(sA + row*64 + ((kk*4+lg)^(row&7))*8);
    }
#pragma unroll
    for (int j = 0; j < 4; j++){
      const int row = wn + j*16 + lr;
      bfv[j] = *(const bf16x8*)(sB + row*64 + ((kk*4+lg)^(row&7))*8);
    }
#pragma unroll
    for (int i = 0; i < 4; i++)
#pragma unroll
      for (int j = 0; j < 4; j++)
        acc[i][j] = MM(af[i], bfv[j], acc[i][j]);
  }
  const int r0 = lg * 4;
#pragma unroll
  for (int j = 0; j < 4; j++){
    const long col = n0 + wn + j*16 + lr;
    const float bv = bias[col];
#pragma unroll
    for (int i = 0; i < 4; i++){
      const long row = m0 + wm + i*16 + r0;
#pragma unroll
      for (int r = 0; r < 4; r++){
        const long rr = row + r;
        if (rr >= MTOK) continue;
        const float v = acc[i][j][r] + bv + pe[(rr % 25)*1024 + col];
        const u16 hv = f2bf(v);
        hf[rr*1024 + col] = v;
        hbf[rr*1024 + col] = hv;
        const long bq = rr / 600, tq = rr % 600;
        xad[((bq*TP1 + 1 + tq) << 10) + col] = hv;
      }
    }
  }
}

// =============== out-projection GEMM: M=9600, N=128(52 valid), K=1024 ==========
__global__ __launch_bounds__(256)
void k_gemm_out(const u16* __restrict__ A, const u16* __restrict__ W,
                const float* __restrict__ bias, float* __restrict__ outp){
  __shared__ u16 sA[128*32];
  __shared__ u16 sB[128*32];
  const int t = threadIdx.x;
  const int w = t >> 6, l = t & 63;
  const long m0 = (long)blockIdx.y * 128;
  const int wm = (w >> 1) << 6, wn = (w & 1) << 6;
  const int K = 1024;
  f32x4 acc[4][4] = {};
  const char* gA0 = (const char*)(A + (m0 + (t >> 2)) * (long)K) + (t & 3) * 16;
  const char* gA1 = gA0 + 64 * (long)K * 2;
  const char* gB0 = (const char*)(W + (long)(t >> 2) * K) + (t & 3) * 16;
  const char* gB1 = gB0 + 64 * (long)K * 2;
  char* lA = (char*)sA + w * 1024;
  char* lB = (char*)sB + w * 1024;
  const int lr = l & 15;
  const int lkb = (l >> 4) * 16;
  for (long k0 = 0; k0 < K; k0 += 32){
    const long kb = k0 * 2;
    gld_lds16(gA0 + kb, lA);
    gld_lds16(gA1 + kb, lA + 4096);
    gld_lds16(gB0 + kb, lB);
    gld_lds16(gB1 + kb, lB + 4096);
    __syncthreads();
    bf16x8 af[4], bfv[4];
#pragma unroll
    for (int i = 0; i < 4; i++)
      af[i] = *(const bf16x8*)((const char*)sA + (wm + i*16 + lr)*64 + lkb);
#pragma unroll
    for (int j = 0; j < 4; j++)
      bfv[j] = *(const bf16x8*)((const char*)sB + (wn + j*16 + lr)*64 + lkb);
#pragma unroll
    for (int i = 0; i < 4; i++)
#pragma unroll
      for (int j = 0; j < 4; j++)
        acc[i][j] = MM(af[i], bfv[j], acc[i][j]);
    __syncthreads();
  }
  const int r0 = (l >> 4) * 4;
#pragma unroll
  for (int j = 0; j < 4; j++){
    const int col = wn + j*16 + lr;
    if (col >= IN_) continue;
    const float bv = bias[col];
#pragma unroll
    for (int i = 0; i < 4; i++){
      const long row = m0 + wm + i*16 + r0;
#pragma unroll
      for (int r = 0; r < 4; r++)
        outp[(row + r) * (long)IN_ + col] = acc[i][j][r] + bv;
    }
  }
}

// ---------------- V transpose: qkv V-part -> vt[b][h][d(128)][VTK keys] ---------
__global__ __launch_bounds__(256)
void k_vtrans(const u16* __restrict__ qkv, u16* __restrict__ vt){
  const int b = blockIdx.z;
  const int h = blockIdx.y >> 1;
  const int d0 = (blockIdx.y & 1) * 64;
  const int k0 = blockIdx.x * 64;
  __shared__ u16 tile[64][72];
  const int t = threadIdx.x;
#pragma unroll
  for (int it = 0; it < 2; it++){
    const int idx = t + it*256;
    const int kk = idx >> 3;
    const int dd = (idx & 7) * 8;
    const int kabs = k0 + kk;
    union { bf16x8 v; u16 us[8]; } u;
    if (kabs <= 600)
      u.v = *(const bf16x8*)(qkv + ((long)b*TP1 + kabs)*3072 + 2048 + h*128 + d0 + dd);
    else {
#pragma unroll
      for (int j = 0; j < 8; j++) u.us[j] = 0;
    }
    *(bf16x8*)(&tile[kk][dd]) = u.v;
  }
  __syncthreads();
#pragma unroll
  for (int it = 0; it < 2; it++){
    const int idx = t + it*256;
    const int dd = idx >> 3;
    const int kc = (idx & 7) * 8;
    if (k0 + kc + 7 < VTK){
      union { uint4 o; u16 us[8]; } u;
#pragma unroll
      for (int j = 0; j < 8; j++) u.us[j] = tile[kc + j][dd];
      *(uint4*)(vt + ((long)(b*8 + h)*128 + d0 + dd)*VTK + k0 + kc) = u.o;
    }
  }
}

// ---------------- self-attention v3 (r15-proven): inline ALiBi + setprio --------
__global__ __launch_bounds__(256)
void k_sa_attn3(const u16* __restrict__ qkv, const u16* __restrict__ vt,
                u16* __restrict__ outp){
  const int id = blockIdx.x;
  const int g  = id & 127;
  const int qt = id >> 7;
  const int b = g >> 3, h = g & 7;
  const int w = threadIdx.x >> 6, l = threadIdx.x & 63;
  const int lr = l & 15, lg = l >> 4;
  const int q0 = qt * 64 + w * 16;
  const float scale = 0.08838834764831845f;
  const float slope = exp2f(-(float)(h + 1));

  __shared__ u16 Kl[2][4096];
  __shared__ u16 Vl[2][4096];
  __shared__ u16 Pl[4][16*40];
  __shared__ float cS[4][16];
  __shared__ float iS[4][16];

  const long bb = (long)b * TP1;
  const u16* qptr = qkv + (bb + 1 + q0 + lr) * 3072 + h * 128 + lg * 8;
  bf16x8 aq[4];
#pragma unroll
  for (int kk = 0; kk < 4; kk++) aq[kk] = *(const bf16x8*)(qptr + kk * 32);

  const int kj0 = w*2, kj1 = w*2 + 1;
  const int kkey0 = kj0*4 + (l >> 4), kkey1 = kj1*4 + (l >> 4);
  const u16* kg0 = qkv + (bb + kkey0)*3072 + 1024 + h*128 + (((l&15) ^ (kkey0&7)))*8;
  const u16* kg1 = qkv + (bb + kkey1)*3072 + 1024 + h*128 + (((l&15) ^ (kkey1&7)))*8;
  const u16* vbase = vt + (long)(b*8 + h) * 128 * VTK;
  const int vd0 = kj0*16 + (l >> 2), vd1 = kj1*16 + (l >> 2);
  const u16* vg0 = vbase + (long)vd0*VTK + ((l&3) ^ ((vd0 >> 1) & 3))*8;
  const u16* vg1 = vbase + (long)vd1*VTK + ((l&3) ^ ((vd1 >> 1) & 3))*8;

#define STAGE(buf, kb) \
  gld_lds16(kg0 + (long)(kb)*3072, (void*)(Kl[buf] + kj0*512)); \
  gld_lds16(kg1 + (long)(kb)*3072, (void*)(Kl[buf] + kj1*512)); \
  gld_lds16(vg0 + (kb),            (void*)(Vl[buf] + kj0*512)); \
  gld_lds16(vg1 + (kb),            (void*)(Vl[buf] + kj1*512));

  f32x4 o[8] = {};
  float mrow[4] = {-1e30f, -1e30f, -1e30f, -1e30f};
  float lsum[4] = {0.f, 0.f, 0.f, 0.f};

  STAGE(0, 0);
  asm volatile("s_waitcnt vmcnt(0)" ::: "memory");
  BAR();

  for (int kt = 0; kt < 19; kt++){
    const int kb0 = kt * 32;
    const int cur = kt & 1;
    const bool st = (kt < 18);
    if (st){ STAGE(cur ^ 1, kb0 + 32); }
    f32x4 s0 = {}, s1 = {};
    __builtin_amdgcn_s_setprio(1);
#pragma unroll
    for (int kk = 0; kk < 4; kk++){
      const int sw = ((kk*4 + lg) ^ (lr & 7)) * 8;
      bf16x8 bk0 = *(const bf16x8*)(Kl[cur] + lr*128 + sw);
      bf16x8 bk1 = *(const bf16x8*)(Kl[cur] + (lr+16)*128 + sw);
      s0 = MM(aq[kk], bk0, s0);
      s1 = MM(aq[kk], bk1, s1);
    }
    __builtin_amdgcn_s_setprio(0);
#pragma unroll
    for (int r = 0; r < 4; r++){
      const int iq = q0 + lg * 4 + r;
      float v0 = s0[r] * scale, v1 = s1[r] * scale;
      const int k0a = kb0 + lr, k1a = kb0 + 16 + lr;
      if (k0a >= 601) v0 = -1e30f;
      else if (k0a > 0){
        const int j = k0a - 1, di = iq - j;
        const int st2 = di >= 0 ? di/25 : (-di-1)/25;
        v0 -= slope * (float)st2;
      }
      if (k1a >= 601) v1 = -1e30f;
      else {
        const int j = k1a - 1, di = iq - j;
        const int st2 = di >= 0 ? di/25 : (-di-1)/25;
        v1 -= slope * (float)st2;
      }
      float mx = fmaxf(v0, v1);
#pragma unroll
      for (int d = 8; d >= 1; d >>= 1) mx = fmaxf(mx, __shfl_xor(mx, d, 64));
      const float mnew = fmaxf(mrow[r], mx);
      const float corr = __expf(mrow[r] - mnew);
      const float p0 = __expf(v0 - mnew);
      const float p1 = __expf(v1 - mnew);
      float rs = p0 + p1;
#pragma unroll
      for (int d = 8; d >= 1; d >>= 1) rs += __shfl_xor(rs, d, 64);
      lsum[r] = lsum[r] * corr + rs;
      mrow[r] = mnew;
      if (lr == 0) cS[w][lg*4 + r] = corr;
      Pl[w][(lg*4 + r)*40 + lr]      = f2bf(p0);
      Pl[w][(lg*4 + r)*40 + 16 + lr] = f2bf(p1);
    }
    const float c = cS[w][lr];
    const bool resc = __any(c != 1.0f);
    const bf16x8 pa = *(const bf16x8*)(&Pl[w][lr*40 + lg*8]);
    __builtin_amdgcn_s_setprio(1);
#pragma unroll
    for (int dc = 0; dc < 8; dc++){
      const int d = dc*16 + lr;
      const bf16x8 va = *(const bf16x8*)(Vl[cur] + d*32 + ((lg ^ ((d >> 1) & 3))*8));
      if (resc){
#pragma unroll
        for (int rr = 0; rr < 4; rr++) o[dc][rr] *= c;
      }
      o[dc] = MM(va, pa, o[dc]);
    }
    __builtin_amdgcn_s_setprio(0);
    if (st){
      asm volatile("s_waitcnt vmcnt(0)" ::: "memory");
      BAR();
    }
  }
#undef STAGE
#pragma unroll
  for (int r = 0; r < 4; r++)
    if (lr == 0) iS[w][lg*4 + r] = 1.f / lsum[r];
  const int tq = q0 + lr;
  if (tq < 600){
    const float inv = iS[w][lr];
    u16* op = outp + ((long)b*600 + tq) * 1024 + h * 128;
#pragma unroll
    for (int dc = 0; dc < 8; dc++){
      union { uint2 o8; u16 us[4]; } pk;
#pragma unroll
      for (int rr = 0; rr < 4; rr++) pk.us[rr] = f2bf(o[dc][rr] * inv);
      *(uint2*)(op + dc*16 + lg*4) = pk.o8;
    }
  }
}

// ---------------- cross-attention: exact 2-key softmax ---------------------------
__global__ __launch_bounds__(256)
void k_ca_attn(const u16* __restrict__ qca, const u16* __restrict__ kv,
               u16* __restrict__ outp){
  const int wid = blockIdx.x * 4 + (threadIdx.x >> 6);
  const int l = threadIdx.x & 63;
  if (wid >= MTOK) return;
  const int b = wid / 600, t = wid % 600;
  const u16* q  = qca + (long)wid * 1024;
  const u16* ka = kv + ((long)b * TP1) * 2048;
  const u16* km = kv + ((long)(b * TP1 + 1 + t)) * 2048;
  const float scale = 0.08838834764831845f;
#pragma unroll
  for (int h = 0; h < 8; h++){
    const int d = h*128 + l*2;
    const float q0 = bf2f(q[d]),  q1 = bf2f(q[d+1]);
    float s0 = q0*bf2f(ka[d]) + q1*bf2f(ka[d+1]);
    float s1 = q0*bf2f(km[d]) + q1*bf2f(km[d+1]);
#pragma unroll
    for (int dd = 32; dd >= 1; dd >>= 1){
      s0 += __shfl_xor(s0, dd, 64);
      s1 += __shfl_xor(s1, dd, 64);
    }
    s0 *= scale; s1 *= scale;
    const float mx = fmaxf(s0, s1);
    const float e0 = __expf(s0 - mx), e1 = __expf(s1 - mx);
    const float inv = 1.f / (e0 + e1);
    const float o0 = (e0*bf2f(ka[1024+d])   + e1*bf2f(km[1024+d]))   * inv;
    const float o1 = (e0*bf2f(ka[1024+d+1]) + e1*bf2f(km[1024+d+1])) * inv;
    const unsigned pack = (unsigned)f2bf(o0) | ((unsigned)f2bf(o1) << 16);
    *(unsigned*)(outp + (long)wid*1024 + d) = pack;
  }
}

// ------- residual-add + in-place LayerNorm (float4); optional xadpt mirror -------
__global__ __launch_bounds__(256)
void k_ln2(float* __restrict__ hf, const u16* __restrict__ sub,
           const float* __restrict__ g, const float* __restrict__ bb,
           u16* __restrict__ hbf, u16* __restrict__ xad){
  const long m = blockIdx.x;
  const int t = threadIdx.x;
  float4* r = (float4*)(hf + m*1024);
  float4 v = r[t];
  union { uint2 u; u16 us[4]; } sv;
  sv.u = *(const uint2*)(sub + m*1024 + t*4);
  v.x += bf2f(sv.us[0]); v.y += bf2f(sv.us[1]);
  v.z += bf2f(sv.us[2]); v.w += bf2f(sv.us[3]);
  float sum = v.x + v.y + v.z + v.w;
  float sumsq = v.x*v.x + v.y*v.y + v.z*v.z + v.w*v.w;
#pragma unroll
  for (int d = 32; d >= 1; d >>= 1){ sum += __shfl_xor(sum,d,64); sumsq += __shfl_xor(sumsq,d,64); }
  __shared__ float red[8];
  const int w = t >> 6;
  if ((t & 63) == 0){ red[w] = sum; red[4+w] = sumsq; }
  __syncthreads();
  sum   = red[0]+red[1]+red[2]+red[3];
  sumsq = red[4]+red[5]+red[6]+red[7];
  const float mu  = sum * (1.f/1024.f);
  const float var = sumsq * (1.f/1024.f) - mu*mu;
  const float rstd = rsqrtf(var + 1e-5f);
  const float4 gv = ((const float4*)g)[t];
  const float4 bv = ((const float4*)bb)[t];
  float4 y;
  y.x = (v.x - mu) * rstd * gv.x + bv.x;
  y.y = (v.y - mu) * rstd * gv.y + bv.y;
  y.z = (v.z - mu) * rstd * gv.z + bv.z;
  y.w = (v.w - mu) * rstd * gv.w + bv.w;
  r[t] = y;
  union { uint2 u; u16 us[4]; } p;
  p.us[0] = f2bf(y.x); p.us[1] = f2bf(y.y); p.us[2] = f2bf(y.z); p.us[3] = f2bf(y.w);
  *(uint2*)(hbf + m*1024 + t*4) = p.u;
  if (xad){
    const long bq = m / 600, tq = m % 600;
    *(uint2*)(xad + ((bq*TP1 + 1 + tq) << 10) + t*4) = p.u;
  }
}

// ---------------- small fp32 kernels ---------------------------------------------
__global__ void k_temb_sin(const int* __restrict__ ts, float* __restrict__ emb){
  const int b = blockIdx.x;
  const float t = (float)ts[b];
  for (int j = threadIdx.x; j < 1024; j += 256){
    const int jj = j < 512 ? j : j - 512;
    const float ex = expf(-9.210340371976184f * (float)jj / 511.0f);
    const float v = t * ex;
    emb[b*1024 + j] = (j < 512) ? sinf(v) : cosf(v);
  }
}

__global__ void k_te_mm(const float* __restrict__ in, const float* __restrict__ W,
                        const float* __restrict__ bv, float* __restrict__ outp,
                        int act, u16* __restrict__ xad, u16* __restrict__ mad){
  __shared__ float row[1024];
  const int b = blockIdx.y;
  for (int k = threadIdx.x; k < 1024; k += 256) row[k] = in[b*1024 + k];
  __syncthreads();
  const int n = blockIdx.x*256 + threadIdx.x;
  const float* wr = W + (long)n*1024;
  float s = 0.f;
  for (int k = 0; k < 1024; k += 4){
    const float4 w4 = *(const float4*)(wr + k);
    s += row[k]*w4.x + row[k+1]*w4.y + row[k+2]*w4.z + row[k+3]*w4.w;
  }
  s += bv[n];
  if (act) s = s / (1.f + expf(-s));   // silu
  outp[b*1024 + n] = s;
  if (xad){
    const u16 h = f2bf(s);
    xad[((long)b*TP1)*1024 + n] = h;
    mad[((long)b*TP1)*1024 + n] = h;
  }
}

// ---------------- data movement / conversion -------------------------------------
__global__ void k_convert_weights(const float* __restrict__ sqkv, const float* __restrict__ swo,
                                  const float* __restrict__ cqkv, const float* __restrict__ cwo,
                                  const float* __restrict__ fw1,  const float* __restrict__ fw2,
                                  u16* __restrict__ wbuf){
  const long idx = ((long)blockIdx.x*256 + threadIdx.x) * 8;
  const float* src; long off;
  if      (idx <  3145728L){ src = sqkv; off = idx; }
  else if (idx <  4194304L){ src = swo;  off = idx -  3145728L; }
  else if (idx <  7340032L){ src = cqkv; off = idx -  4194304L; }
  else if (idx <  8388608L){ src = cwo;  off = idx -  7340032L; }
  else if (idx < 12582912L){ src = fw1;  off = idx -  8388608L; }
  else                     { src = fw2;  off = idx - 12582912L; }
  const float4 a = *(const float4*)(src + off);
  const float4 c = *(const float4*)(src + off + 4);
  uint4 o;
  o.x = (unsigned)f2bf(a.x) | ((unsigned)f2bf(a.y) << 16);
  o.y = (unsigned)f2bf(a.z) | ((unsigned)f2bf(a.w) << 16);
  o.z = (unsigned)f2bf(c.x) | ((unsigned)f2bf(c.y) << 16);
  o.w = (unsigned)f2bf(c.z) | ((unsigned)f2bf(c.w) << 16);
  *(uint4*)(wbuf + idx) = o;
}

__global__ void k_convert_wout(const float* __restrict__ src, u16* __restrict__ dst){
  const int i = blockIdx.x*256 + threadIdx.x;   // 131072 total
  const int row = i >> 10;
  dst[i] = (row < IN_) ? f2bf(src[i]) : (u16)0;
}

__global__ void k_convert_x(const float* __restrict__ x, u16* __restrict__ dst){
  const int i = blockIdx.x*256 + threadIdx.x;   // MPAD*64 = 622592
  const int row = i >> 6, c = i & 63;
  float v = 0.f;
  if (row < MTOK && c < IN_) v = x[(long)row*IN_ + c];
  dst[i] = f2bf(v);
}

__global__ void k_convert_win(const float* __restrict__ wi, u16* __restrict__ dst){
  const int i = blockIdx.x*256 + threadIdx.x;   // 1024*64 = 65536
  const int row = i >> 6, c = i & 63;
  dst[i] = (c < IN_) ? f2bf(wi[(long)row*IN_ + c]) : (u16)0;
}

__global__ void k_build_memadpt(const float* __restrict__ mem, u16* __restrict__ mad){
  const long i = ((long)blockIdx.x*256 + threadIdx.x) * 8;
  const long tok = i >> 10, col = i & 1023;
  const long b = tok / 600, s = tok % 600;
  const float4 a = *(const float4*)(mem + i);
  const float4 c = *(const float4*)(mem + i + 4);
  uint4 o;
  o.x = (unsigned)f2bf(a.x) | ((unsigned)f2bf(a.y) << 16);
  o.y = (unsigned)f2bf(a.z) | ((unsigned)f2bf(a.w) << 16);
  o.z = (unsigned)f2bf(c.x) | ((unsigned)f2bf(c.y) << 16);
  o.w = (unsigned)f2bf(c.z) | ((unsigned)f2bf(c.w) << 16);
  *(uint4*)(mad + ((b*TP1 + 1 + s) << 10) + col) = o;
}

// ---------------- host-side launch -----------------------------------------------
extern "C" void kernel_launch(void* const* d_in, const int* in_sizes, int n_in,
                              void* d_out, int out_size, void* d_ws, size_t ws_size,
                              hipStream_t stream){
  const float* x        = (const float*)d_in[0];
  const float* memory   = (const float*)d_in[1];
  const int*   tsteps   = (const int*)  d_in[2];
  const float* pe       = (const float*)d_in[3];
  const float* W_in     = (const float*)d_in[5];
  const float* b_in     = (const float*)d_in[6];
  const float* te_W1    = (const float*)d_in[7];
  const float* te_b1    = (const float*)d_in[8];
  const float* te_W2    = (const float*)d_in[9];
  const float* te_b2    = (const float*)d_in[10];
  const float* sa_Wqkv  = (const float*)d_in[11];
  const float* sa_bqkv  = (const float*)d_in[12];
  const float* sa_Wo    = (const float*)d_in[13];
  const float* sa_bo    = (const float*)d_in[14];
  const float* ca_Wqkv  = (const float*)d_in[15];
  const float* ca_bqkv  = (const float*)d_in[16];
  const float* ca_Wo    = (const float*)d_in[17];
  const float* ca_bo    = (const float*)d_in[18];
  const float* ff_W1    = (const float*)d_in[19];
  const float* ff_b1    = (const float*)d_in[20];
  const float* ff_W2    = (const float*)d_in[21];
  const float* ff_b2    = (const float*)d_in[22];
  const float* ln1_g    = (const float*)d_in[23];
  const float* ln2_g    = (const float*)d_in[24];
  const float* ln3_g    = (const float*)d_in[25];
  const float* ln1_b    = (const float*)d_in[26];
  const float* ln2_b    = (const float*)d_in[27];
  const float* ln3_b    = (const float*)d_in[28];
  const float* W_out    = (const float*)d_in[29];
  const float* b_out    = (const float*)d_in[30];

  char* ws = (char*)d_ws;   // ~311 MB used
  float* h_f    = (float*)(ws + 0);            //  9600x1024 f32
  u16*   h_bf   = (u16*)  (ws + 39321600);     //  9600x1024 bf16
  u16*   attn_bf= (u16*)  (ws + 58982400);     //  9600x1024
  u16*   xadpt  = (u16*)  (ws + 78643200);     //  9616x1024
  u16*   madpt  = (u16*)  (ws + 98336768);     //  9616x1024
  u16*   qkv    = (u16*)  (ws + 118030336);    //  MPADx3072
  u16*   ffb    = (u16*)  (ws + 177799168);    //  MPADx4096
  u16*   wbuf   = (u16*)  (ws + 257490944);    //  16.7M bf16
  u16*   sub_bf = (u16*)  (ws + 291045376);    //  MPADx1024 bf16 (GEMM C for residual)
  float* temb_a = (float*)(ws + 177799168);    //  alias ffb (prologue only)
  float* temb_b = (float*)(ws + 177864704);
  u16*   vtg    = (u16*)  (ws + 177799168 + 262144); // alias ffb (dead before FF1)
  u16*   x_bf   = wbuf;                        //  alias wbuf (prologue only) MPADx64
  u16*   win_bf = wbuf + 622592;               //  1024x64
  u16*   wout_bf= wbuf;                        //  reuse after layer loop

  u16* qca  = qkv;                             // 9600x1024 (token-major)
  u16* kvca = qkv + (long)MPAD * 1024;         // MPADx2048 (adapter-major)

  // time-embed + adapter + input projection (MFMA path)
  k_temb_sin<<<dim3(16), dim3(256), 0, stream>>>(tsteps, temb_a);
  k_te_mm<<<dim3(4,16), dim3(256), 0, stream>>>(temb_a, te_W1, te_b1, temb_b, 1, (u16*)nullptr, (u16*)nullptr);
  k_te_mm<<<dim3(4,16), dim3(256), 0, stream>>>(temb_b, te_W2, te_b2, temb_a, 0, xadpt, madpt);
  k_build_memadpt<<<dim3(4800), dim3(256), 0, stream>>>(memory, madpt);
  k_convert_x<<<dim3(2432), dim3(256), 0, stream>>>(x, x_bf);
  k_convert_win<<<dim3(256), dim3(256), 0, stream>>>(W_in, win_bf);
  k_gemm_in<<<dim3(8,76), dim3(256), 0, stream>>>(x_bf, win_bf, b_in, pe, h_f, h_bf, xadpt);

  for (int l = 0; l < L_; l++){
    k_convert_weights<<<dim3(8192), dim3(256), 0, stream>>>(
        sa_Wqkv + (long)l*3145728, sa_Wo + (long)l*1048576,
        ca_Wqkv + (long)l*3145728, ca_Wo + (long)l*1048576,
        ff_W1 + (long)l*4194304,  ff_W2 + (long)l*4194304, wbuf);
    // --- self attention (xadpt maintained by k_gemm_in / ln3 of prev layer) ---
    k_gemm256<0><<<dim3(12,38), dim3(512), 0, stream>>>(xadpt, wbuf, sa_bqkv + l*3072, (void*)qkv, 3072, 1024);
    k_vtrans<<<dim3(10,16,16), dim3(256), 0, stream>>>(qkv, vtg);
    k_sa_attn3<<<dim3(1280), dim3(256), 0, stream>>>(qkv, vtg, attn_bf);
    k_gemm_n128<0><<<dim3(8,76), dim3(256), 0, stream>>>(attn_bf, wbuf + 3145728, sa_bo + l*1024, (void*)sub_bf, 1024, 1024);
    k_ln2<<<dim3(9600), dim3(256), 0, stream>>>(h_f, sub_bf, ln1_g + l*1024, ln1_b + l*1024, h_bf, (u16*)nullptr);
    // --- cross attention (adapter + diagonal only) ---
    k_gemm_n128<0><<<dim3(8,76), dim3(256), 0, stream>>>(h_bf, wbuf + 4194304, ca_bqkv + l*3072, (void*)qca, 1024, 1024);
    k_gemm_n128<0><<<dim3(16,76), dim3(256), 0, stream>>>(madpt, wbuf + 4194304 + 1048576, ca_bqkv + l*3072 + 1024, (void*)kvca, 2048, 1024);
    k_ca_attn<<<dim3(2400), dim3(256), 0, stream>>>(qca, kvca, attn_bf);
    k_gemm_n128<0><<<dim3(8,76), dim3(256), 0, stream>>>(attn_bf, wbuf + 7340032, ca_bo + l*1024, (void*)sub_bf, 1024, 1024);
    k_ln2<<<dim3(9600), dim3(256), 0, stream>>>(h_f, sub_bf, ln2_g + l*1024, ln2_b + l*1024, h_bf, (u16*)nullptr);
    // --- feed forward ---
    k_gemm256<1><<<dim3(16,38), dim3(512), 0, stream>>>(h_bf, wbuf + 8388608, ff_b1 + l*4096, (void*)ffb, 4096, 1024);
    k_gemm_n128<0><<<dim3(8,76), dim3(256), 0, stream>>>(ffb, wbuf + 12582912, ff_b2 + l*1024, (void*)sub_bf, 1024, 4096);
    k_ln2<<<dim3(9600), dim3(256), 0, stream>>>(h_f, sub_bf, ln3_g + l*1024, ln3_b + l*1024, h_bf, xadpt);
  }
  k_convert_wout<<<dim3(512), dim3(256), 0, stream>>>(W_out, wout_bf);
  k_gemm_out<<<dim3(1,75), dim3(256), 0, stream>>>(h_bf, wout_bf, b_out, (float*)d_out);
}

// Round 18
// 4961.303 us; speedup vs baseline: 1.1076x; 1.0224x over previous
//
#include <hip/hip_runtime.h>
#include <stdint.h>

#define B_ 16
#define T_ 600
#define S_ 600
#define D_ 1024
#define H_ 8
#define HD_ 128
#define L_ 8
#define DFF_ 4096
#define IN_ 52
#define TP1 601
#define MTOK 9600   // B*T
#define MPAD 9728   // 38*256 padded rows
#define VTK 608     // padded key count for V^T

typedef unsigned short u16;
typedef float f32x4 __attribute__((ext_vector_type(4)));
typedef __bf16 bf16x8 __attribute__((ext_vector_type(8)));

__device__ __forceinline__ u16 f2bf(float f){
  union { float f; unsigned u; } v; v.f = f;
  v.u += 0x7FFFu + ((v.u >> 16) & 1u);
  return (u16)(v.u >> 16);
}
__device__ __forceinline__ float bf2f(u16 h){
  union { unsigned u; float f; } v; v.u = ((unsigned)h) << 16;
  return v.f;
}
__device__ __forceinline__ void gld_lds16(const void* g, void* l){
  __builtin_amdgcn_global_load_lds(
      (const __attribute__((address_space(1))) void*)(uintptr_t)g,
      (__attribute__((address_space(3))) void*)(uintptr_t)l, 16, 0, 0);
}
__device__ __forceinline__ f32x4 MM(bf16x8 a, bf16x8 b, f32x4 c){
  return __builtin_amdgcn_mfma_f32_16x16x32_bf16(a, b, c, 0, 0, 0);
}
#define BAR() asm volatile("s_barrier" ::: "memory")

// =============== 256x256 GEMM, BK=64, 8 waves, early-issue schedule ============
// EPI: 0 = bf16 out, 1 = relu+bf16. Epilogue: C tile packed to LDS (128KB) then
// full-line uint4 stores.
template<int EPI>
__global__ __launch_bounds__(512, 2)
void k_gemm256(const u16* __restrict__ A, const u16* __restrict__ W,
               const float* __restrict__ bias, void* __restrict__ Cout,
               int N, int K){
  __shared__ u16 lds[65536];                 // 128 KiB: 2 bufs x (A 16384 + B 16384) u16
  const int t = threadIdx.x;
  const int w = t >> 6, l = t & 63;
  const int lr = l & 15, lg = l >> 4;
  const int wr = w >> 2, wc = w & 3;

  int lin = blockIdx.y * gridDim.x + blockIdx.x;
  const int nwg = gridDim.x * gridDim.y;
  lin = (lin & 7) * (nwg >> 3) + (lin >> 3);
  const long m0 = (long)(lin / gridDim.x) * 256;
  const long n0 = (long)(lin % gridDim.x) * 256;

  const int srow = w*8 + (l >> 3);
  const int schk = (l & 7) ^ (l >> 3);
  const u16* gA = A + (m0 + srow) * (long)K + schk * 8;
  const u16* gB = W + (n0 + srow) * (long)K + schk * 8;

  const int chk0 = ((    lg) ^ (lr & 7)) * 8;
  const int chk1 = ((4 + lg) ^ (lr & 7)) * 8;
  const int arow = (wr*128 + lr) * 64;
  const int brow = (wc*64  + lr) * 64 + 16384;

  f32x4 acc[8][4] = {};
  const int NT = K >> 6;

#define STG_A(i) gld_lds16(gA + (long)(i)*64*K + nc, (void*)(lds + nb + (i)*4096 + w*512))
#define STG_B(i) gld_lds16(gB + (long)(i)*64*K + nc, (void*)(lds + nb + 16384 + (i)*4096 + w*512))
#define LOADF(mq, CH) \
    a0 = *(const bf16x8*)(lds + bufo + arow + ((mq)*4+0)*1024 + (CH)); \
    a1 = *(const bf16x8*)(lds + bufo + arow + ((mq)*4+1)*1024 + (CH)); \
    a2 = *(const bf16x8*)(lds + bufo + arow + ((mq)*4+2)*1024 + (CH)); \
    a3 = *(const bf16x8*)(lds + bufo + arow + ((mq)*4+3)*1024 + (CH)); \
    b0 = *(const bf16x8*)(lds + bufo + brow + 0*1024 + (CH)); \
    b1 = *(const bf16x8*)(lds + bufo + brow + 1*1024 + (CH)); \
    b2 = *(const bf16x8*)(lds + bufo + brow + 2*1024 + (CH));  \
    b3 = *(const bf16x8*)(lds + bufo + brow + 3*1024 + (CH));
#define MFMA16(mq) \
    __builtin_amdgcn_s_setprio(1); \
    { const bf16x8 aa[4] = {a0,a1,a2,a3}; const bf16x8 bb4[4] = {b0,b1,b2,b3}; \
      _Pragma("unroll") for (int i_ = 0; i_ < 4; i_++) \
        _Pragma("unroll") for (int j_ = 0; j_ < 4; j_++) \
          acc[(mq)*4+i_][j_] = MM(aa[i_], bb4[j_], acc[(mq)*4+i_][j_]); } \
    __builtin_amdgcn_s_setprio(0);

  { const int nb = 0; const long nc = 0;
    STG_B(0); STG_B(1); STG_B(2); STG_B(3);
    STG_A(0); STG_A(1); STG_A(2); STG_A(3);
  }
  asm volatile("s_waitcnt vmcnt(0)" ::: "memory");
  BAR();

  int bufo = 0;
  for (int tt = 0; tt < NT; ++tt){
    const int nb = bufo ^ 32768;
    const bool st = (tt + 1 < NT);
    const long nc = (long)(tt + 1) * 64;
    bf16x8 a0,a1,a2,a3,b0,b1,b2,b3;
    LOADF(0, chk0);
    if (st){ STG_B(0); STG_B(1); STG_B(2); STG_B(3); }
    BAR();
    MFMA16(0);
    BAR();
    LOADF(0, chk1);
    if (st){ STG_A(0); STG_A(1); STG_A(2); STG_A(3); }
    BAR();
    MFMA16(0);
    BAR();
    LOADF(1, chk0);
    BAR();
    MFMA16(1);
    BAR();
    LOADF(1, chk1);
    asm volatile("s_waitcnt vmcnt(0)" ::: "memory");
    BAR();
    MFMA16(1);
    BAR();
    bufo = nb;
  }
#undef STG_A
#undef STG_B
#undef LOADF
#undef MFMA16

  const int r4 = lg * 4;
  // pack bf16 C tile into LDS (chunk-XOR swizzled), then full-line stores
#pragma unroll
  for (int nf = 0; nf < 4; nf++){
    const int colt = wc*64 + nf*16 + lr;           // tile col 0..255
    const float bv = bias[n0 + colt];
#pragma unroll
    for (int mf = 0; mf < 8; mf++){
      const int rowt = wr*128 + mf*16 + r4;
#pragma unroll
      for (int r = 0; r < 4; r++){
        float v = acc[mf][nf][r] + bv;
        if (EPI == 1) v = fmaxf(v, 0.f);
        const int row = rowt + r;
        lds[row*256 + (((colt >> 3) ^ (row & 7)) << 3) + (colt & 7)] = f2bf(v);
      }
    }
  }
  BAR();
  u16* cbase = (u16*)Cout + n0;
#pragma unroll
  for (int pass = 0; pass < 2; pass++){
#pragma unroll
    for (int it = 0; it < 8; it++){
      const int row = it*32 + w*4 + (l >> 4);
      const int ck  = (l & 15) + pass*16;
      const uint4 v = *(const uint4*)(lds + row*256 + ((ck ^ (row & 7)) << 3));
      *(uint4*)(cbase + (m0 + row) * (long)N + ck*8) = v;
    }
  }
}

// =============== 128x128 GEMM: 4 waves x 64x64, BK=32, 4 blocks/CU ==============
// 2:1 MFMA:ds_read at 16 waves/CU. bf16 epilogue via LDS (32KB full-line stores).
template<int EPI>
__global__ __launch_bounds__(256, 4)
void k_gemm_n128(const u16* __restrict__ A, const u16* __restrict__ W,
                 const float* __restrict__ bias, void* __restrict__ Cout,
                 int N, int K){
  __shared__ u16 lds[16384];                 // 32 KiB: 2 bufs x (A 4096 + B 4096) u16
  const int t = threadIdx.x;
  const int w = t >> 6, l = t & 63;
  const int lr = l & 15, lg = l >> 4;
  const int wr = w >> 1, wc = w & 1;

  int lin = blockIdx.y * gridDim.x + blockIdx.x;
  const int nwg = gridDim.x * gridDim.y;
  lin = (lin & 7) * (nwg >> 3) + (lin >> 3);
  const long m0 = (long)(lin / gridDim.x) * 128;
  const long n0 = (long)(lin % gridDim.x) * 128;

  const int schk = (t & 3) ^ ((t >> 3) & 3);
  const u16* gA = A + (m0 + (t >> 2)) * (long)K + schk * 8;
  const u16* gB = W + (n0 + (t >> 2)) * (long)K + schk * 8;

  const int ch = (lg ^ ((lr >> 1) & 3)) * 8;
  const int aoff = wr*2048 + lr*32 + ch;          // + mf*512
  const int boff = 4096 + wc*2048 + lr*32 + ch;   // + nf*512

  f32x4 acc[4][4] = {};
  const int NT = K >> 5;

#define STG128(nb, nc) \
    gld_lds16(gA + (nc),              (void*)(lds + (nb) + 0    + w*512)); \
    gld_lds16(gA + 64*(long)K + (nc), (void*)(lds + (nb) + 2048 + w*512)); \
    gld_lds16(gB + (nc),              (void*)(lds + (nb) + 4096 + w*512)); \
    gld_lds16(gB + 64*(long)K + (nc), (void*)(lds + (nb) + 6144 + w*512));

  STG128(0, 0);
  asm volatile("s_waitcnt vmcnt(0)" ::: "memory");
  BAR();

  int bufo = 0;
  for (int tt = 0; tt < NT; ++tt){
    const int nb = bufo ^ 8192;
    const bool st = (tt + 1 < NT);
    const long nc = (long)(tt + 1) * 32;
    if (st){ STG128(nb, nc); }
    bf16x8 a0,a1,a2,a3,b0,b1,b2,b3;
    a0 = *(const bf16x8*)(lds + bufo + aoff + 0*512);
    a1 = *(const bf16x8*)(lds + bufo + aoff + 1*512);
    a2 = *(const bf16x8*)(lds + bufo + aoff + 2*512);
    a3 = *(const bf16x8*)(lds + bufo + aoff + 3*512);
    b0 = *(const bf16x8*)(lds + bufo + boff + 0*512);
    b1 = *(const bf16x8*)(lds + bufo + boff + 1*512);
    b2 = *(const bf16x8*)(lds + bufo + boff + 2*512);
    b3 = *(const bf16x8*)(lds + bufo + boff + 3*512);
    __builtin_amdgcn_s_setprio(1);
    acc[0][0] = MM(a0,b0,acc[0][0]); acc[0][1] = MM(a0,b1,acc[0][1]);
    acc[0][2] = MM(a0,b2,acc[0][2]); acc[0][3] = MM(a0,b3,acc[0][3]);
    acc[1][0] = MM(a1,b0,acc[1][0]); acc[1][1] = MM(a1,b1,acc[1][1]);
    acc[1][2] = MM(a1,b2,acc[1][2]); acc[1][3] = MM(a1,b3,acc[1][3]);
    acc[2][0] = MM(a2,b0,acc[2][0]); acc[2][1] = MM(a2,b1,acc[2][1]);
    acc[2][2] = MM(a2,b2,acc[2][2]); acc[2][3] = MM(a2,b3,acc[2][3]);
    acc[3][0] = MM(a3,b0,acc[3][0]); acc[3][1] = MM(a3,b1,acc[3][1]);
    acc[3][2] = MM(a3,b2,acc[3][2]); acc[3][3] = MM(a3,b3,acc[3][3]);
    __builtin_amdgcn_s_setprio(0);
    if (st) asm volatile("s_waitcnt vmcnt(0)" ::: "memory");
    BAR();
    bufo = nb;
  }
#undef STG128

  const int r4 = lg * 4;
#pragma unroll
  for (int nf = 0; nf < 4; nf++){
    const int colt = wc*64 + nf*16 + lr;           // tile col 0..127
    const float bv = bias[n0 + colt];
#pragma unroll
    for (int mf = 0; mf < 4; mf++){
      const int rowt = wr*64 + mf*16 + r4;
#pragma unroll
      for (int r = 0; r < 4; r++){
        float v = acc[mf][nf][r] + bv;
        if (EPI == 1) v = fmaxf(v, 0.f);
        const int row = rowt + r;
        lds[row*128 + (((colt >> 3) ^ (row & 7)) << 3) + (colt & 7)] = f2bf(v);
      }
    }
  }
  BAR();
  u16* cbase = (u16*)Cout + n0;
#pragma unroll
  for (int it = 0; it < 8; it++){
    const int row = it*16 + w*4 + (l >> 4);
    const int ck  = l & 15;
    const uint4 v = *(const uint4*)(lds + row*128 + ((ck ^ (row & 7)) << 3));
    *(uint4*)(cbase + (m0 + row) * (long)N + ck*8) = v;
  }
}

// =============== input projection GEMM: h = x(Mx64) * W_in(1024x64)^T + b + pe ==
__global__ __launch_bounds__(256)
void k_gemm_in(const u16* __restrict__ A, const u16* __restrict__ W,
               const float* __restrict__ bias, const float* __restrict__ pe,
               float* __restrict__ hf, u16* __restrict__ hbf, u16* __restrict__ xad){
  __shared__ u16 sA[128*64];
  __shared__ u16 sB[128*64];
  const int t = threadIdx.x;
  const int w = t >> 6, l = t & 63;
  const int lr = l & 15, lg = l >> 4;
  const long m0 = (long)blockIdx.y * 128;
  const long n0 = (long)blockIdx.x * 128;
  const int wm = (w >> 1) << 6, wn = (w & 1) << 6;
  const int srow = t >> 3;                   // 0..31 per issue
  const int schk = (t & 7) ^ (srow & 7);
  const u16* gA = A + (m0 + srow) * 64 + schk * 8;
  const u16* gB = W + (n0 + srow) * 64 + schk * 8;
#pragma unroll
  for (int i = 0; i < 4; i++){
    gld_lds16(gA + i*32*64, (void*)(sA + i*2048 + (t>>6)*512));
    gld_lds16(gB + i*32*64, (void*)(sB + i*2048 + (t>>6)*512));
  }
  asm volatile("s_waitcnt vmcnt(0)" ::: "memory");
  __syncthreads();
  f32x4 acc[4][4] = {};
#pragma unroll
  for (int kk = 0; kk < 2; kk++){
    bf16x8 af[4], bfv[4];
#pragma unroll
    for (int i = 0; i < 4; i++){
      const int row = wm + i*16 + lr;
      af[i] = *(const bf16x8*)(sA + row*64 + ((kk*4+lg)^(row&7))*8);
    }
#pragma unroll
    for (int j = 0; j < 4; j++){
      const int row = wn + j*16 + lr;
      bfv[j] = *(const bf16x8*)(sB + row*64 + ((kk*4+lg)^(row&7))*8);
    }
#pragma unroll
    for (int i = 0; i < 4; i++)
#pragma unroll
      for (int j = 0; j < 4; j++)
        acc[i][j] = MM(af[i], bfv[j], acc[i][j]);
  }
  const int r0 = lg * 4;
#pragma unroll
  for (int j = 0; j < 4; j++){
    const long col = n0 + wn + j*16 + lr;
    const float bv = bias[col];
#pragma unroll
    for (int i = 0; i < 4; i++){
      const long row = m0 + wm + i*16 + r0;
#pragma unroll
      for (int r = 0; r < 4; r++){
        const long rr = row + r;
        if (rr >= MTOK) continue;
        const float v = acc[i][j][r] + bv + pe[(rr % 25)*1024 + col];
        const u16 hv = f2bf(v);
        hf[rr*1024 + col] = v;
        hbf[rr*1024 + col] = hv;
        const long bq = rr / 600, tq = rr % 600;
        xad[((bq*TP1 + 1 + tq) << 10) + col] = hv;
      }
    }
  }
}

// =============== out-projection GEMM: M=9600, N=128(52 valid), K=1024 ==========
__global__ __launch_bounds__(256)
void k_gemm_out(const u16* __restrict__ A, const u16* __restrict__ W,
                const float* __restrict__ bias, float* __restrict__ outp){
  __shared__ u16 sA[128*32];
  __shared__ u16 sB[128*32];
  const int t = threadIdx.x;
  const int w = t >> 6, l = t & 63;
  const long m0 = (long)blockIdx.y * 128;
  const int wm = (w >> 1) << 6, wn = (w & 1) << 6;
  const int K = 1024;
  f32x4 acc[4][4] = {};
  const char* gA0 = (const char*)(A + (m0 + (t >> 2)) * (long)K) + (t & 3) * 16;
  const char* gA1 = gA0 + 64 * (long)K * 2;
  const char* gB0 = (const char*)(W + (long)(t >> 2) * K) + (t & 3) * 16;
  const char* gB1 = gB0 + 64 * (long)K * 2;
  char* lA = (char*)sA + w * 1024;
  char* lB = (char*)sB + w * 1024;
  const int lr = l & 15;
  const int lkb = (l >> 4) * 16;
  for (long k0 = 0; k0 < K; k0 += 32){
    const long kb = k0 * 2;
    gld_lds16(gA0 + kb, lA);
    gld_lds16(gA1 + kb, lA + 4096);
    gld_lds16(gB0 + kb, lB);
    gld_lds16(gB1 + kb, lB + 4096);
    __syncthreads();
    bf16x8 af[4], bfv[4];
#pragma unroll
    for (int i = 0; i < 4; i++)
      af[i] = *(const bf16x8*)((const char*)sA + (wm + i*16 + lr)*64 + lkb);
#pragma unroll
    for (int j = 0; j < 4; j++)
      bfv[j] = *(const bf16x8*)((const char*)sB + (wn + j*16 + lr)*64 + lkb);
#pragma unroll
    for (int i = 0; i < 4; i++)
#pragma unroll
      for (int j = 0; j < 4; j++)
        acc[i][j] = MM(af[i], bfv[j], acc[i][j]);
    __syncthreads();
  }
  const int r0 = (l >> 4) * 4;
#pragma unroll
  for (int j = 0; j < 4; j++){
    const int col = wn + j*16 + lr;
    if (col >= IN_) continue;
    const float bv = bias[col];
#pragma unroll
    for (int i = 0; i < 4; i++){
      const long row = m0 + wm + i*16 + r0;
#pragma unroll
      for (int r = 0; r < 4; r++)
        outp[(row + r) * (long)IN_ + col] = acc[i][j][r] + bv;
    }
  }
}

// ---------------- V transpose: qkv V-part -> vt[b][h][d(128)][VTK keys] ---------
__global__ __launch_bounds__(256)
void k_vtrans(const u16* __restrict__ qkv, u16* __restrict__ vt){
  const int b = blockIdx.z;
  const int h = blockIdx.y >> 1;
  const int d0 = (blockIdx.y & 1) * 64;
  const int k0 = blockIdx.x * 64;
  __shared__ u16 tile[64][72];
  const int t = threadIdx.x;
#pragma unroll
  for (int it = 0; it < 2; it++){
    const int idx = t + it*256;
    const int kk = idx >> 3;
    const int dd = (idx & 7) * 8;
    const int kabs = k0 + kk;
    union { bf16x8 v; u16 us[8]; } u;
    if (kabs <= 600)
      u.v = *(const bf16x8*)(qkv + ((long)b*TP1 + kabs)*3072 + 2048 + h*128 + d0 + dd);
    else {
#pragma unroll
      for (int j = 0; j < 8; j++) u.us[j] = 0;
    }
    *(bf16x8*)(&tile[kk][dd]) = u.v;
  }
  __syncthreads();
#pragma unroll
  for (int it = 0; it < 2; it++){
    const int idx = t + it*256;
    const int dd = idx >> 3;
    const int kc = (idx & 7) * 8;
    if (k0 + kc + 7 < VTK){
      union { uint4 o; u16 us[8]; } u;
#pragma unroll
      for (int j = 0; j < 8; j++) u.us[j] = tile[kc + j][dd];
      *(uint4*)(vt + ((long)(b*8 + h)*128 + d0 + dd)*VTK + k0 + kc) = u.o;
    }
  }
}

// ---------------- self-attention v5: MFMA row-sum softmax -----------------------
// Sum-reduction done by matrix pipe: mfma(ones, P^T, 0) -> per-q tile sums.
// Removes 16 shfl + 16 add per tile from the serial VALU chain.
__global__ __launch_bounds__(256)
void k_sa_attn3(const u16* __restrict__ qkv, const u16* __restrict__ vt,
                u16* __restrict__ outp){
  const int id = blockIdx.x;
  const int g  = id & 127;
  const int qt = id >> 7;
  const int b = g >> 3, h = g & 7;
  const int w = threadIdx.x >> 6, l = threadIdx.x & 63;
  const int lr = l & 15, lg = l >> 4;
  const int q0 = qt * 64 + w * 16;
  const float scale = 0.08838834764831845f;
  const float slope = exp2f(-(float)(h + 1));

  __shared__ u16 Kl[2][4096];
  __shared__ u16 Vl[2][4096];
  __shared__ u16 Pl[4][16*40];
  __shared__ float cS[4][16];

  const long bb = (long)b * TP1;
  const u16* qptr = qkv + (bb + 1 + q0 + lr) * 3072 + h * 128 + lg * 8;
  bf16x8 aq[4];
#pragma unroll
  for (int kk = 0; kk < 4; kk++) aq[kk] = *(const bf16x8*)(qptr + kk * 32);

  // all-ones bf16 A-fragment for the row-sum MFMA
  bf16x8 ones;
#pragma unroll
  for (int i = 0; i < 8; i++) ones[i] = (__bf16)1.0f;

  const int kj0 = w*2, kj1 = w*2 + 1;
  const int kkey0 = kj0*4 + (l >> 4), kkey1 = kj1*4 + (l >> 4);
  const u16* kg0 = qkv + (bb + kkey0)*3072 + 1024 + h*128 + (((l&15) ^ (kkey0&7)))*8;
  const u16* kg1 = qkv + (bb + kkey1)*3072 + 1024 + h*128 + (((l&15) ^ (kkey1&7)))*8;
  const u16* vbase = vt + (long)(b*8 + h) * 128 * VTK;
  const int vd0 = kj0*16 + (l >> 2), vd1 = kj1*16 + (l >> 2);
  const u16* vg0 = vbase + (long)vd0*VTK + ((l&3) ^ ((vd0 >> 1) & 3))*8;
  const u16* vg1 = vbase + (long)vd1*VTK + ((l&3) ^ ((vd1 >> 1) & 3))*8;

#define STAGE(buf, kb) \
  gld_lds16(kg0 + (long)(kb)*3072, (void*)(Kl[buf] + kj0*512)); \
  gld_lds16(kg1 + (long)(kb)*3072, (void*)(Kl[buf] + kj1*512)); \
  gld_lds16(vg0 + (kb),            (void*)(Vl[buf] + kj0*512)); \
  gld_lds16(vg1 + (kb),            (void*)(Vl[buf] + kj1*512));

  f32x4 o[8] = {};
  float mrow[4] = {-1e30f, -1e30f, -1e30f, -1e30f};
  float lsumq = 0.f;                          // running denom for q = lr

  STAGE(0, 0);
  asm volatile("s_waitcnt vmcnt(0)" ::: "memory");
  BAR();

  for (int kt = 0; kt < 19; kt++){
    const int kb0 = kt * 32;
    const int cur = kt & 1;
    const bool st = (kt < 18);
    if (st){ STAGE(cur ^ 1, kb0 + 32); }
    f32x4 s0 = {}, s1 = {};
    __builtin_amdgcn_s_setprio(1);
#pragma unroll
    for (int kk = 0; kk < 4; kk++){
      const int sw = ((kk*4 + lg) ^ (lr & 7)) * 8;
      bf16x8 bk0 = *(const bf16x8*)(Kl[cur] + lr*128 + sw);
      bf16x8 bk1 = *(const bf16x8*)(Kl[cur] + (lr+16)*128 + sw);
      s0 = MM(aq[kk], bk0, s0);
      s1 = MM(aq[kk], bk1, s1);
    }
    __builtin_amdgcn_s_setprio(0);
#pragma unroll
    for (int r = 0; r < 4; r++){
      const int iq = q0 + lg * 4 + r;
      float v0 = s0[r] * scale, v1 = s1[r] * scale;
      const int k0a = kb0 + lr, k1a = kb0 + 16 + lr;
      if (k0a >= 601) v0 = -1e30f;
      else if (k0a > 0){
        const int j = k0a - 1, di = iq - j;
        const int st2 = di >= 0 ? di/25 : (-di-1)/25;
        v0 -= slope * (float)st2;
      }
      if (k1a >= 601) v1 = -1e30f;
      else {
        const int j = k1a - 1, di = iq - j;
        const int st2 = di >= 0 ? di/25 : (-di-1)/25;
        v1 -= slope * (float)st2;
      }
      float mx = fmaxf(v0, v1);
#pragma unroll
      for (int d = 8; d >= 1; d >>= 1) mx = fmaxf(mx, __shfl_xor(mx, d, 64));
      const float mnew = fmaxf(mrow[r], mx);
      const float corr = __expf(mrow[r] - mnew);
      const float p0 = __expf(v0 - mnew);
      const float p1 = __expf(v1 - mnew);
      mrow[r] = mnew;
      if (lr == 0) cS[w][lg*4 + r] = corr;
      Pl[w][(lg*4 + r)*40 + lr]      = f2bf(p0);
      Pl[w][(lg*4 + r)*40 + 16 + lr] = f2bf(p1);
    }
    const float c = cS[w][lr];
    const bool resc = __any(c != 1.0f);
    const bf16x8 pa = *(const bf16x8*)(&Pl[w][lr*40 + lg*8]);
    // denom via matrix pipe: D[row][q=lr] = sum_k P[q][k] (rows identical)
    f32x4 zz = {0.f, 0.f, 0.f, 0.f};
    f32x4 sacc = MM(ones, pa, zz);
    lsumq = lsumq * c + sacc[0];
    __builtin_amdgcn_s_setprio(1);
#pragma unroll
    for (int dc = 0; dc < 8; dc++){
      const int d = dc*16 + lr;
      const bf16x8 va = *(const bf16x8*)(Vl[cur] + d*32 + ((lg ^ ((d >> 1) & 3))*8));
      if (resc){
#pragma unroll
        for (int rr = 0; rr < 4; rr++) o[dc][rr] *= c;
      }
      o[dc] = MM(va, pa, o[dc]);
    }
    __builtin_amdgcn_s_setprio(0);
    if (st){
      asm volatile("s_waitcnt vmcnt(0)" ::: "memory");
      BAR();
    }
  }
#undef STAGE
  const int tq = q0 + lr;
  if (tq < 600){
    const float inv = 1.f / lsumq;
    u16* op = outp + ((long)b*600 + tq) * 1024 + h * 128;
#pragma unroll
    for (int dc = 0; dc < 8; dc++){
      union { uint2 o8; u16 us[4]; } pk;
#pragma unroll
      for (int rr = 0; rr < 4; rr++) pk.us[rr] = f2bf(o[dc][rr] * inv);
      *(uint2*)(op + dc*16 + lg*4) = pk.o8;
    }
  }
}

// ---------------- cross-attention: exact 2-key softmax ---------------------------
__global__ __launch_bounds__(256)
void k_ca_attn(const u16* __restrict__ qca, const u16* __restrict__ kv,
               u16* __restrict__ outp){
  const int wid = blockIdx.x * 4 + (threadIdx.x >> 6);
  const int l = threadIdx.x & 63;
  if (wid >= MTOK) return;
  const int b = wid / 600, t = wid % 600;
  const u16* q  = qca + (long)wid * 1024;
  const u16* ka = kv + ((long)b * TP1) * 2048;
  const u16* km = kv + ((long)(b * TP1 + 1 + t)) * 2048;
  const float scale = 0.08838834764831845f;
#pragma unroll
  for (int h = 0; h < 8; h++){
    const int d = h*128 + l*2;
    const float q0 = bf2f(q[d]),  q1 = bf2f(q[d+1]);
    float s0 = q0*bf2f(ka[d]) + q1*bf2f(ka[d+1]);
    float s1 = q0*bf2f(km[d]) + q1*bf2f(km[d+1]);
#pragma unroll
    for (int dd = 32; dd >= 1; dd >>= 1){
      s0 += __shfl_xor(s0, dd, 64);
      s1 += __shfl_xor(s1, dd, 64);
    }
    s0 *= scale; s1 *= scale;
    const float mx = fmaxf(s0, s1);
    const float e0 = __expf(s0 - mx), e1 = __expf(s1 - mx);
    const float inv = 1.f / (e0 + e1);
    const float o0 = (e0*bf2f(ka[1024+d])   + e1*bf2f(km[1024+d]))   * inv;
    const float o1 = (e0*bf2f(ka[1024+d+1]) + e1*bf2f(km[1024+d+1])) * inv;
    const unsigned pack = (unsigned)f2bf(o0) | ((unsigned)f2bf(o1) << 16);
    *(unsigned*)(outp + (long)wid*1024 + d) = pack;
  }
}

// ------- residual-add + in-place LayerNorm (float4); optional xadpt mirror -------
__global__ __launch_bounds__(256)
void k_ln2(float* __restrict__ hf, const u16* __restrict__ sub,
           const float* __restrict__ g, const float* __restrict__ bb,
           u16* __restrict__ hbf, u16* __restrict__ xad){
  const long m = blockIdx.x;
  const int t = threadIdx.x;
  float4* r = (float4*)(hf + m*1024);
  float4 v = r[t];
  union { uint2 u; u16 us[4]; } sv;
  sv.u = *(const uint2*)(sub + m*1024 + t*4);
  v.x += bf2f(sv.us[0]); v.y += bf2f(sv.us[1]);
  v.z += bf2f(sv.us[2]); v.w += bf2f(sv.us[3]);
  float sum = v.x + v.y + v.z + v.w;
  float sumsq = v.x*v.x + v.y*v.y + v.z*v.z + v.w*v.w;
#pragma unroll
  for (int d = 32; d >= 1; d >>= 1){ sum += __shfl_xor(sum,d,64); sumsq += __shfl_xor(sumsq,d,64); }
  __shared__ float red[8];
  const int w = t >> 6;
  if ((t & 63) == 0){ red[w] = sum; red[4+w] = sumsq; }
  __syncthreads();
  sum   = red[0]+red[1]+red[2]+red[3];
  sumsq = red[4]+red[5]+red[6]+red[7];
  const float mu  = sum * (1.f/1024.f);
  const float var = sumsq * (1.f/1024.f) - mu*mu;
  const float rstd = rsqrtf(var + 1e-5f);
  const float4 gv = ((const float4*)g)[t];
  const float4 bv = ((const float4*)bb)[t];
  float4 y;
  y.x = (v.x - mu) * rstd * gv.x + bv.x;
  y.y = (v.y - mu) * rstd * gv.y + bv.y;
  y.z = (v.z - mu) * rstd * gv.z + bv.z;
  y.w = (v.w - mu) * rstd * gv.w + bv.w;
  r[t] = y;
  union { uint2 u; u16 us[4]; } p;
  p.us[0] = f2bf(y.x); p.us[1] = f2bf(y.y); p.us[2] = f2bf(y.z); p.us[3] = f2bf(y.w);
  *(uint2*)(hbf + m*1024 + t*4) = p.u;
  if (xad){
    const long bq = m / 600, tq = m % 600;
    *(uint2*)(xad + ((bq*TP1 + 1 + tq) << 10) + t*4) = p.u;
  }
}

// ---------------- small fp32 kernels ---------------------------------------------
__global__ void k_temb_sin(const int* __restrict__ ts, float* __restrict__ emb){
  const int b = blockIdx.x;
  const float t = (float)ts[b];
  for (int j = threadIdx.x; j < 1024; j += 256){
    const int jj = j < 512 ? j : j - 512;
    const float ex = expf(-9.210340371976184f * (float)jj / 511.0f);
    const float v = t * ex;
    emb[b*1024 + j] = (j < 512) ? sinf(v) : cosf(v);
  }
}

__global__ void k_te_mm(const float* __restrict__ in, const float* __restrict__ W,
                        const float* __restrict__ bv, float* __restrict__ outp,
                        int act, u16* __restrict__ xad, u16* __restrict__ mad){
  __shared__ float row[1024];
  const int b = blockIdx.y;
  for (int k = threadIdx.x; k < 1024; k += 256) row[k] = in[b*1024 + k];
  __syncthreads();
  const int n = blockIdx.x*256 + threadIdx.x;
  const float* wr = W + (long)n*1024;
  float s = 0.f;
  for (int k = 0; k < 1024; k += 4){
    const float4 w4 = *(const float4*)(wr + k);
    s += row[k]*w4.x + row[k+1]*w4.y + row[k+2]*w4.z + row[k+3]*w4.w;
  }
  s += bv[n];
  if (act) s = s / (1.f + expf(-s));   // silu
  outp[b*1024 + n] = s;
  if (xad){
    const u16 h = f2bf(s);
    xad[((long)b*TP1)*1024 + n] = h;
    mad[((long)b*TP1)*1024 + n] = h;
  }
}

// ---------------- data movement / conversion -------------------------------------
__global__ void k_convert_weights(const float* __restrict__ sqkv, const float* __restrict__ swo,
                                  const float* __restrict__ cqkv, const float* __restrict__ cwo,
                                  const float* __restrict__ fw1,  const float* __restrict__ fw2,
                                  u16* __restrict__ wbuf){
  const long idx = ((long)blockIdx.x*256 + threadIdx.x) * 8;
  const float* src; long off;
  if      (idx <  3145728L){ src = sqkv; off = idx; }
  else if (idx <  4194304L){ src = swo;  off = idx -  3145728L; }
  else if (idx <  7340032L){ src = cqkv; off = idx -  4194304L; }
  else if (idx <  8388608L){ src = cwo;  off = idx -  7340032L; }
  else if (idx < 12582912L){ src = fw1;  off = idx -  8388608L; }
  else                     { src = fw2;  off = idx - 12582912L; }
  const float4 a = *(const float4*)(src + off);
  const float4 c = *(const float4*)(src + off + 4);
  uint4 o;
  o.x = (unsigned)f2bf(a.x) | ((unsigned)f2bf(a.y) << 16);
  o.y = (unsigned)f2bf(a.z) | ((unsigned)f2bf(a.w) << 16);
  o.z = (unsigned)f2bf(c.x) | ((unsigned)f2bf(c.y) << 16);
  o.w = (unsigned)f2bf(c.z) | ((unsigned)f2bf(c.w) << 16);
  *(uint4*)(wbuf + idx) = o;
}

__global__ void k_convert_wout(const float* __restrict__ src, u16* __restrict__ dst){
  const int i = blockIdx.x*256 + threadIdx.x;   // 131072 total
  const int row = i >> 10;
  dst[i] = (row < IN_) ? f2bf(src[i]) : (u16)0;
}

__global__ void k_convert_x(const float* __restrict__ x, u16* __restrict__ dst){
  const int i = blockIdx.x*256 + threadIdx.x;   // MPAD*64 = 622592
  const int row = i >> 6, c = i & 63;
  float v = 0.f;
  if (row < MTOK && c < IN_) v = x[(long)row*IN_ + c];
  dst[i] = f2bf(v);
}

__global__ void k_convert_win(const float* __restrict__ wi, u16* __restrict__ dst){
  const int i = blockIdx.x*256 + threadIdx.x;   // 1024*64 = 65536
  const int row = i >> 6, c = i & 63;
  dst[i] = (c < IN_) ? f2bf(wi[(long)row*IN_ + c]) : (u16)0;
}

__global__ void k_build_memadpt(const float* __restrict__ mem, u16* __restrict__ mad){
  const long i = ((long)blockIdx.x*256 + threadIdx.x) * 8;
  const long tok = i >> 10, col = i & 1023;
  const long b = tok / 600, s = tok % 600;
  const float4 a = *(const float4*)(mem + i);
  const float4 c = *(const float4*)(mem + i + 4);
  uint4 o;
  o.x = (unsigned)f2bf(a.x) | ((unsigned)f2bf(a.y) << 16);
  o.y = (unsigned)f2bf(a.z) | ((unsigned)f2bf(a.w) << 16);
  o.z = (unsigned)f2bf(c.x) | ((unsigned)f2bf(c.y) << 16);
  o.w = (unsigned)f2bf(c.z) | ((unsigned)f2bf(c.w) << 16);
  *(uint4*)(mad + ((b*TP1 + 1 + s) << 10) + col) = o;
}

// ---------------- host-side launch -----------------------------------------------
extern "C" void kernel_launch(void* const* d_in, const int* in_sizes, int n_in,
                              void* d_out, int out_size, void* d_ws, size_t ws_size,
                              hipStream_t stream){
  const float* x        = (const float*)d_in[0];
  const float* memory   = (const float*)d_in[1];
  const int*   tsteps   = (const int*)  d_in[2];
  const float* pe       = (const float*)d_in[3];
  const float* W_in     = (const float*)d_in[5];
  const float* b_in     = (const float*)d_in[6];
  const float* te_W1    = (const float*)d_in[7];
  const float* te_b1    = (const float*)d_in[8];
  const float* te_W2    = (const float*)d_in[9];
  const float* te_b2    = (const float*)d_in[10];
  const float* sa_Wqkv  = (const float*)d_in[11];
  const float* sa_bqkv  = (const float*)d_in[12];
  const float* sa_Wo    = (const float*)d_in[13];
  const float* sa_bo    = (const float*)d_in[14];
  const float* ca_Wqkv  = (const float*)d_in[15];
  const float* ca_bqkv  = (const float*)d_in[16];
  const float* ca_Wo    = (const float*)d_in[17];
  const float* ca_bo    = (const float*)d_in[18];
  const float* ff_W1    = (const float*)d_in[19];
  const float* ff_b1    = (const float*)d_in[20];
  const float* ff_W2    = (const float*)d_in[21];
  const float* ff_b2    = (const float*)d_in[22];
  const float* ln1_g    = (const float*)d_in[23];
  const float* ln2_g    = (const float*)d_in[24];
  const float* ln3_g    = (const float*)d_in[25];
  const float* ln1_b    = (const float*)d_in[26];
  const float* ln2_b    = (const float*)d_in[27];
  const float* ln3_b    = (const float*)d_in[28];
  const float* W_out    = (const float*)d_in[29];
  const float* b_out    = (const float*)d_in[30];

  char* ws = (char*)d_ws;   // ~311 MB used
  float* h_f    = (float*)(ws + 0);            //  9600x1024 f32
  u16*   h_bf   = (u16*)  (ws + 39321600);     //  9600x1024 bf16
  u16*   attn_bf= (u16*)  (ws + 58982400);     //  9600x1024
  u16*   xadpt  = (u16*)  (ws + 78643200);     //  9616x1024
  u16*   madpt  = (u16*)  (ws + 98336768);     //  9616x1024
  u16*   qkv    = (u16*)  (ws + 118030336);    //  MPADx3072
  u16*   ffb    = (u16*)  (ws + 177799168);    //  MPADx4096
  u16*   wbuf   = (u16*)  (ws + 257490944);    //  16.7M bf16
  u16*   sub_bf = (u16*)  (ws + 291045376);    //  MPADx1024 bf16 (GEMM C for residual)
  float* temb_a = (float*)(ws + 177799168);    //  alias ffb (prologue only)
  float* temb_b = (float*)(ws + 177864704);
  u16*   vtg    = (u16*)  (ws + 177799168 + 262144); // alias ffb (dead before FF1)
  u16*   x_bf   = wbuf;                        //  alias wbuf (prologue only) MPADx64
  u16*   win_bf = wbuf + 622592;               //  1024x64
  u16*   wout_bf= wbuf;                        //  reuse after layer loop

  u16* qca  = qkv;                             // 9600x1024 (token-major)
  u16* kvca = qkv + (long)MPAD * 1024;         // MPADx2048 (adapter-major)

  // time-embed + adapter + input projection (MFMA path)
  k_temb_sin<<<dim3(16), dim3(256), 0, stream>>>(tsteps, temb_a);
  k_te_mm<<<dim3(4,16), dim3(256), 0, stream>>>(temb_a, te_W1, te_b1, temb_b, 1, (u16*)nullptr, (u16*)nullptr);
  k_te_mm<<<dim3(4,16), dim3(256), 0, stream>>>(temb_b, te_W2, te_b2, temb_a, 0, xadpt, madpt);
  k_build_memadpt<<<dim3(4800), dim3(256), 0, stream>>>(memory, madpt);
  k_convert_x<<<dim3(2432), dim3(256), 0, stream>>>(x, x_bf);
  k_convert_win<<<dim3(256), dim3(256), 0, stream>>>(W_in, win_bf);
  k_gemm_in<<<dim3(8,76), dim3(256), 0, stream>>>(x_bf, win_bf, b_in, pe, h_f, h_bf, xadpt);

  for (int l = 0; l < L_; l++){
    k_convert_weights<<<dim3(8192), dim3(256), 0, stream>>>(
        sa_Wqkv + (long)l*3145728, sa_Wo + (long)l*1048576,
        ca_Wqkv + (long)l*3145728, ca_Wo + (long)l*1048576,
        ff_W1 + (long)l*4194304,  ff_W2 + (long)l*4194304, wbuf);
    // --- self attention (xadpt maintained by k_gemm_in / ln3 of prev layer) ---
    k_gemm256<0><<<dim3(12,38), dim3(512), 0, stream>>>(xadpt, wbuf, sa_bqkv + l*3072, (void*)qkv, 3072, 1024);
    k_vtrans<<<dim3(10,16,16), dim3(256), 0, stream>>>(qkv, vtg);
    k_sa_attn3<<<dim3(1280), dim3(256), 0, stream>>>(qkv, vtg, attn_bf);
    k_gemm_n128<0><<<dim3(8,76), dim3(256), 0, stream>>>(attn_bf, wbuf + 3145728, sa_bo + l*1024, (void*)sub_bf, 1024, 1024);
    k_ln2<<<dim3(9600), dim3(256), 0, stream>>>(h_f, sub_bf, ln1_g + l*1024, ln1_b + l*1024, h_bf, (u16*)nullptr);
    // --- cross attention (adapter + diagonal only) ---
    k_gemm_n128<0><<<dim3(8,76), dim3(256), 0, stream>>>(h_bf, wbuf + 4194304, ca_bqkv + l*3072, (void*)qca, 1024, 1024);
    k_gemm_n128<0><<<dim3(16,76), dim3(256), 0, stream>>>(madpt, wbuf + 4194304 + 1048576, ca_bqkv + l*3072 + 1024, (void*)kvca, 2048, 1024);
    k_ca_attn<<<dim3(2400), dim3(256), 0, stream>>>(qca, kvca, attn_bf);
    k_gemm_n128<0><<<dim3(8,76), dim3(256), 0, stream>>>(attn_bf, wbuf + 7340032, ca_bo + l*1024, (void*)sub_bf, 1024, 1024);
    k_ln2<<<dim3(9600), dim3(256), 0, stream>>>(h_f, sub_bf, ln2_g + l*1024, ln2_b + l*1024, h_bf, (u16*)nullptr);
    // --- feed forward ---
    k_gemm256<1><<<dim3(16,38), dim3(512), 0, stream>>>(h_bf, wbuf + 8388608, ff_b1 + l*4096, (void*)ffb, 4096, 1024);
    k_gemm_n128<0><<<dim3(8,76), dim3(256), 0, stream>>>(ffb, wbuf + 12582912, ff_b2 + l*1024, (void*)sub_bf, 1024, 4096);
    k_ln2<<<dim3(9600), dim3(256), 0, stream>>>(h_f, sub_bf, ln3_g + l*1024, ln3_b + l*1024, h_bf, xadpt);
  }
  k_convert_wout<<<dim3(512), dim3(256), 0, stream>>>(W_out, wout_bf);
  k_gemm_out<<<dim3(1,75), dim3(256), 0, stream>>>(h_bf, wout_bf, b_out, (float*)d_out);
}

// Round 19
// 4804.507 us; speedup vs baseline: 1.1437x; 1.0326x over previous
//
#include <hip/hip_runtime.h>
#include <stdint.h>

#define B_ 16
#define T_ 600
#define S_ 600
#define D_ 1024
#define H_ 8
#define HD_ 128
#define L_ 8
#define DFF_ 4096
#define IN_ 52
#define TP1 601
#define MTOK 9600   // B*T
#define MPAD 9728   // 38*256 padded rows
#define VTK 608     // padded key count for V^T

typedef unsigned short u16;
typedef float f32x4 __attribute__((ext_vector_type(4)));
typedef __bf16 bf16x8 __attribute__((ext_vector_type(8)));

__device__ __forceinline__ u16 f2bf(float f){
  union { float f; unsigned u; } v; v.f = f;
  v.u += 0x7FFFu + ((v.u >> 16) & 1u);
  return (u16)(v.u >> 16);
}
__device__ __forceinline__ float bf2f(u16 h){
  union { unsigned u; float f; } v; v.u = ((unsigned)h) << 16;
  return v.f;
}
__device__ __forceinline__ void gld_lds16(const void* g, void* l){
  __builtin_amdgcn_global_load_lds(
      (const __attribute__((address_space(1))) void*)(uintptr_t)g,
      (__attribute__((address_space(3))) void*)(uintptr_t)l, 16, 0, 0);
}
__device__ __forceinline__ f32x4 MM(bf16x8 a, bf16x8 b, f32x4 c){
  return __builtin_amdgcn_mfma_f32_16x16x32_bf16(a, b, c, 0, 0, 0);
}
#define BAR() asm volatile("s_barrier" ::: "memory")

// =============== 256x256 GEMM, BK=64, 8 waves, early-issue schedule ============
// EPI: 0 = bf16 out, 1 = relu+bf16. Epilogue: C tile packed to LDS (128KB) then
// full-line uint4 stores.
template<int EPI>
__global__ __launch_bounds__(512, 2)
void k_gemm256(const u16* __restrict__ A, const u16* __restrict__ W,
               const float* __restrict__ bias, void* __restrict__ Cout,
               int N, int K){
  __shared__ u16 lds[65536];                 // 128 KiB: 2 bufs x (A 16384 + B 16384) u16
  const int t = threadIdx.x;
  const int w = t >> 6, l = t & 63;
  const int lr = l & 15, lg = l >> 4;
  const int wr = w >> 2, wc = w & 3;

  int lin = blockIdx.y * gridDim.x + blockIdx.x;
  const int nwg = gridDim.x * gridDim.y;
  lin = (lin & 7) * (nwg >> 3) + (lin >> 3);
  const long m0 = (long)(lin / gridDim.x) * 256;
  const long n0 = (long)(lin % gridDim.x) * 256;

  const int srow = w*8 + (l >> 3);
  const int schk = (l & 7) ^ (l >> 3);
  const u16* gA = A + (m0 + srow) * (long)K + schk * 8;
  const u16* gB = W + (n0 + srow) * (long)K + schk * 8;

  const int chk0 = ((    lg) ^ (lr & 7)) * 8;
  const int chk1 = ((4 + lg) ^ (lr & 7)) * 8;
  const int arow = (wr*128 + lr) * 64;
  const int brow = (wc*64  + lr) * 64 + 16384;

  f32x4 acc[8][4] = {};
  const int NT = K >> 6;

#define STG_A(i) gld_lds16(gA + (long)(i)*64*K + nc, (void*)(lds + nb + (i)*4096 + w*512))
#define STG_B(i) gld_lds16(gB + (long)(i)*64*K + nc, (void*)(lds + nb + 16384 + (i)*4096 + w*512))
#define LOADF(mq, CH) \
    a0 = *(const bf16x8*)(lds + bufo + arow + ((mq)*4+0)*1024 + (CH)); \
    a1 = *(const bf16x8*)(lds + bufo + arow + ((mq)*4+1)*1024 + (CH)); \
    a2 = *(const bf16x8*)(lds + bufo + arow + ((mq)*4+2)*1024 + (CH)); \
    a3 = *(const bf16x8*)(lds + bufo + arow + ((mq)*4+3)*1024 + (CH)); \
    b0 = *(const bf16x8*)(lds + bufo + brow + 0*1024 + (CH)); \
    b1 = *(const bf16x8*)(lds + bufo + brow + 1*1024 + (CH)); \
    b2 = *(const bf16x8*)(lds + bufo + brow + 2*1024 + (CH));  \
    b3 = *(const bf16x8*)(lds + bufo + brow + 3*1024 + (CH));
#define MFMA16(mq) \
    __builtin_amdgcn_s_setprio(1); \
    { const bf16x8 aa[4] = {a0,a1,a2,a3}; const bf16x8 bb4[4] = {b0,b1,b2,b3}; \
      _Pragma("unroll") for (int i_ = 0; i_ < 4; i_++) \
        _Pragma("unroll") for (int j_ = 0; j_ < 4; j_++) \
          acc[(mq)*4+i_][j_] = MM(aa[i_], bb4[j_], acc[(mq)*4+i_][j_]); } \
    __builtin_amdgcn_s_setprio(0);

  { const int nb = 0; const long nc = 0;
    STG_B(0); STG_B(1); STG_B(2); STG_B(3);
    STG_A(0); STG_A(1); STG_A(2); STG_A(3);
  }
  asm volatile("s_waitcnt vmcnt(0)" ::: "memory");
  BAR();

  int bufo = 0;
  for (int tt = 0; tt < NT; ++tt){
    const int nb = bufo ^ 32768;
    const bool st = (tt + 1 < NT);
    const long nc = (long)(tt + 1) * 64;
    bf16x8 a0,a1,a2,a3,b0,b1,b2,b3;
    LOADF(0, chk0);
    if (st){ STG_B(0); STG_B(1); STG_B(2); STG_B(3); }
    BAR();
    MFMA16(0);
    BAR();
    LOADF(0, chk1);
    if (st){ STG_A(0); STG_A(1); STG_A(2); STG_A(3); }
    BAR();
    MFMA16(0);
    BAR();
    LOADF(1, chk0);
    BAR();
    MFMA16(1);
    BAR();
    LOADF(1, chk1);
    asm volatile("s_waitcnt vmcnt(0)" ::: "memory");
    BAR();
    MFMA16(1);
    BAR();
    bufo = nb;
  }
#undef STG_A
#undef STG_B
#undef LOADF
#undef MFMA16

  const int r4 = lg * 4;
  // pack bf16 C tile into LDS (chunk-XOR swizzled), then full-line stores
#pragma unroll
  for (int nf = 0; nf < 4; nf++){
    const int colt = wc*64 + nf*16 + lr;           // tile col 0..255
    const float bv = bias[n0 + colt];
#pragma unroll
    for (int mf = 0; mf < 8; mf++){
      const int rowt = wr*128 + mf*16 + r4;
#pragma unroll
      for (int r = 0; r < 4; r++){
        float v = acc[mf][nf][r] + bv;
        if (EPI == 1) v = fmaxf(v, 0.f);
        const int row = rowt + r;
        lds[row*256 + (((colt >> 3) ^ (row & 7)) << 3) + (colt & 7)] = f2bf(v);
      }
    }
  }
  BAR();
  u16* cbase = (u16*)Cout + n0;
#pragma unroll
  for (int pass = 0; pass < 2; pass++){
#pragma unroll
    for (int it = 0; it < 8; it++){
      const int row = it*32 + w*4 + (l >> 4);
      const int ck  = (l & 15) + pass*16;
      const uint4 v = *(const uint4*)(lds + row*256 + ((ck ^ (row & 7)) << 3));
      *(uint4*)(cbase + (m0 + row) * (long)N + ck*8) = v;
    }
  }
}

// =============== 128x128 GEMM: 4 waves x 64x64, BK=32, 4 blocks/CU ==============
// 2:1 MFMA:ds_read at 16 waves/CU. bf16 epilogue via LDS (32KB full-line stores).
template<int EPI>
__global__ __launch_bounds__(256, 4)
void k_gemm_n128(const u16* __restrict__ A, const u16* __restrict__ W,
                 const float* __restrict__ bias, void* __restrict__ Cout,
                 int N, int K){
  __shared__ u16 lds[16384];                 // 32 KiB: 2 bufs x (A 4096 + B 4096) u16
  const int t = threadIdx.x;
  const int w = t >> 6, l = t & 63;
  const int lr = l & 15, lg = l >> 4;
  const int wr = w >> 1, wc = w & 1;

  int lin = blockIdx.y * gridDim.x + blockIdx.x;
  const int nwg = gridDim.x * gridDim.y;
  lin = (lin & 7) * (nwg >> 3) + (lin >> 3);
  const long m0 = (long)(lin / gridDim.x) * 128;
  const long n0 = (long)(lin % gridDim.x) * 128;

  const int schk = (t & 3) ^ ((t >> 3) & 3);
  const u16* gA = A + (m0 + (t >> 2)) * (long)K + schk * 8;
  const u16* gB = W + (n0 + (t >> 2)) * (long)K + schk * 8;

  const int ch = (lg ^ ((lr >> 1) & 3)) * 8;
  const int aoff = wr*2048 + lr*32 + ch;          // + mf*512
  const int boff = 4096 + wc*2048 + lr*32 + ch;   // + nf*512

  f32x4 acc[4][4] = {};
  const int NT = K >> 5;

#define STG128(nb, nc) \
    gld_lds16(gA + (nc),              (void*)(lds + (nb) + 0    + w*512)); \
    gld_lds16(gA + 64*(long)K + (nc), (void*)(lds + (nb) + 2048 + w*512)); \
    gld_lds16(gB + (nc),              (void*)(lds + (nb) + 4096 + w*512)); \
    gld_lds16(gB + 64*(long)K + (nc), (void*)(lds + (nb) + 6144 + w*512));

  STG128(0, 0);
  asm volatile("s_waitcnt vmcnt(0)" ::: "memory");
  BAR();

  int bufo = 0;
  for (int tt = 0; tt < NT; ++tt){
    const int nb = bufo ^ 8192;
    const bool st = (tt + 1 < NT);
    const long nc = (long)(tt + 1) * 32;
    if (st){ STG128(nb, nc); }
    bf16x8 a0,a1,a2,a3,b0,b1,b2,b3;
    a0 = *(const bf16x8*)(lds + bufo + aoff + 0*512);
    a1 = *(const bf16x8*)(lds + bufo + aoff + 1*512);
    a2 = *(const bf16x8*)(lds + bufo + aoff + 2*512);
    a3 = *(const bf16x8*)(lds + bufo + aoff + 3*512);
    b0 = *(const bf16x8*)(lds + bufo + boff + 0*512);
    b1 = *(const bf16x8*)(lds + bufo + boff + 1*512);
    b2 = *(const bf16x8*)(lds + bufo + boff + 2*512);
    b3 = *(const bf16x8*)(lds + bufo + boff + 3*512);
    __builtin_amdgcn_s_setprio(1);
    acc[0][0] = MM(a0,b0,acc[0][0]); acc[0][1] = MM(a0,b1,acc[0][1]);
    acc[0][2] = MM(a0,b2,acc[0][2]); acc[0][3] = MM(a0,b3,acc[0][3]);
    acc[1][0] = MM(a1,b0,acc[1][0]); acc[1][1] = MM(a1,b1,acc[1][1]);
    acc[1][2] = MM(a1,b2,acc[1][2]); acc[1][3] = MM(a1,b3,acc[1][3]);
    acc[2][0] = MM(a2,b0,acc[2][0]); acc[2][1] = MM(a2,b1,acc[2][1]);
    acc[2][2] = MM(a2,b2,acc[2][2]); acc[2][3] = MM(a2,b3,acc[2][3]);
    acc[3][0] = MM(a3,b0,acc[3][0]); acc[3][1] = MM(a3,b1,acc[3][1]);
    acc[3][2] = MM(a3,b2,acc[3][2]); acc[3][3] = MM(a3,b3,acc[3][3]);
    __builtin_amdgcn_s_setprio(0);
    if (st) asm volatile("s_waitcnt vmcnt(0)" ::: "memory");
    BAR();
    bufo = nb;
  }
#undef STG128

  const int r4 = lg * 4;
#pragma unroll
  for (int nf = 0; nf < 4; nf++){
    const int colt = wc*64 + nf*16 + lr;           // tile col 0..127
    const float bv = bias[n0 + colt];
#pragma unroll
    for (int mf = 0; mf < 4; mf++){
      const int rowt = wr*64 + mf*16 + r4;
#pragma unroll
      for (int r = 0; r < 4; r++){
        float v = acc[mf][nf][r] + bv;
        if (EPI == 1) v = fmaxf(v, 0.f);
        const int row = rowt + r;
        lds[row*128 + (((colt >> 3) ^ (row & 7)) << 3) + (colt & 7)] = f2bf(v);
      }
    }
  }
  BAR();
  u16* cbase = (u16*)Cout + n0;
#pragma unroll
  for (int it = 0; it < 8; it++){
    const int row = it*16 + w*4 + (l >> 4);
    const int ck  = l & 15;
    const uint4 v = *(const uint4*)(lds + row*128 + ((ck ^ (row & 7)) << 3));
    *(uint4*)(cbase + (m0 + row) * (long)N + ck*8) = v;
  }
}

// =============== input projection GEMM: h = x(Mx64) * W_in(1024x64)^T + b + pe ==
__global__ __launch_bounds__(256)
void k_gemm_in(const u16* __restrict__ A, const u16* __restrict__ W,
               const float* __restrict__ bias, const float* __restrict__ pe,
               float* __restrict__ hf, u16* __restrict__ hbf, u16* __restrict__ xad){
  __shared__ u16 sA[128*64];
  __shared__ u16 sB[128*64];
  const int t = threadIdx.x;
  const int w = t >> 6, l = t & 63;
  const int lr = l & 15, lg = l >> 4;
  const long m0 = (long)blockIdx.y * 128;
  const long n0 = (long)blockIdx.x * 128;
  const int wm = (w >> 1) << 6, wn = (w & 1) << 6;
  const int srow = t >> 3;                   // 0..31 per issue
  const int schk = (t & 7) ^ (srow & 7);
  const u16* gA = A + (m0 + srow) * 64 + schk * 8;
  const u16* gB = W + (n0 + srow) * 64 + schk * 8;
#pragma unroll
  for (int i = 0; i < 4; i++){
    gld_lds16(gA + i*32*64, (void*)(sA + i*2048 + (t>>6)*512));
    gld_lds16(gB + i*32*64, (void*)(sB + i*2048 + (t>>6)*512));
  }
  asm volatile("s_waitcnt vmcnt(0)" ::: "memory");
  __syncthreads();
  f32x4 acc[4][4] = {};
#pragma unroll
  for (int kk = 0; kk < 2; kk++){
    bf16x8 af[4], bfv[4];
#pragma unroll
    for (int i = 0; i < 4; i++){
      const int row = wm + i*16 + lr;
      af[i] = *(const bf16x8*)(sA + row*64 + ((kk*4+lg)^(row&7))*8);
    }
#pragma unroll
    for (int j = 0; j < 4; j++){
      const int row = wn + j*16 + lr;
      bfv[j] = *(const bf16x8*)(sB + row*64 + ((kk*4+lg)^(row&7))*8);
    }
#pragma unroll
    for (int i = 0; i < 4; i++)
#pragma unroll
      for (int j = 0; j < 4; j++)
        acc[i][j] = MM(af[i], bfv[j], acc[i][j]);
  }
  const int r0 = lg * 4;
#pragma unroll
  for (int j = 0; j < 4; j++){
    const long col = n0 + wn + j*16 + lr;
    const float bv = bias[col];
#pragma unroll
    for (int i = 0; i < 4; i++){
      const long row = m0 + wm + i*16 + r0;
#pragma unroll
      for (int r = 0; r < 4; r++){
        const long rr = row + r;
        if (rr >= MTOK) continue;
        const float v = acc[i][j][r] + bv + pe[(rr % 25)*1024 + col];
        const u16 hv = f2bf(v);
        hf[rr*1024 + col] = v;
        hbf[rr*1024 + col] = hv;
        const long bq = rr / 600, tq = rr % 600;
        xad[((bq*TP1 + 1 + tq) << 10) + col] = hv;
      }
    }
  }
}

// =============== out-projection GEMM: M=9600, N=128(52 valid), K=1024 ==========
__global__ __launch_bounds__(256)
void k_gemm_out(const u16* __restrict__ A, const u16* __restrict__ W,
                const float* __restrict__ bias, float* __restrict__ outp){
  __shared__ u16 sA[128*32];
  __shared__ u16 sB[128*32];
  const int t = threadIdx.x;
  const int w = t >> 6, l = t & 63;
  const long m0 = (long)blockIdx.y * 128;
  const int wm = (w >> 1) << 6, wn = (w & 1) << 6;
  const int K = 1024;
  f32x4 acc[4][4] = {};
  const char* gA0 = (const char*)(A + (m0 + (t >> 2)) * (long)K) + (t & 3) * 16;
  const char* gA1 = gA0 + 64 * (long)K * 2;
  const char* gB0 = (const char*)(W + (long)(t >> 2) * K) + (t & 3) * 16;
  const char* gB1 = gB0 + 64 * (long)K * 2;
  char* lA = (char*)sA + w * 1024;
  char* lB = (char*)sB + w * 1024;
  const int lr = l & 15;
  const int lkb = (l >> 4) * 16;
  for (long k0 = 0; k0 < K; k0 += 32){
    const long kb = k0 * 2;
    gld_lds16(gA0 + kb, lA);
    gld_lds16(gA1 + kb, lA + 4096);
    gld_lds16(gB0 + kb, lB);
    gld_lds16(gB1 + kb, lB + 4096);
    __syncthreads();
    bf16x8 af[4], bfv[4];
#pragma unroll
    for (int i = 0; i < 4; i++)
      af[i] = *(const bf16x8*)((const char*)sA + (wm + i*16 + lr)*64 + lkb);
#pragma unroll
    for (int j = 0; j < 4; j++)
      bfv[j] = *(const bf16x8*)((const char*)sB + (wn + j*16 + lr)*64 + lkb);
#pragma unroll
    for (int i = 0; i < 4; i++)
#pragma unroll
      for (int j = 0; j < 4; j++)
        acc[i][j] = MM(af[i], bfv[j], acc[i][j]);
    __syncthreads();
  }
  const int r0 = (l >> 4) * 4;
#pragma unroll
  for (int j = 0; j < 4; j++){
    const int col = wn + j*16 + lr;
    if (col >= IN_) continue;
    const float bv = bias[col];
#pragma unroll
    for (int i = 0; i < 4; i++){
      const long row = m0 + wm + i*16 + r0;
#pragma unroll
      for (int r = 0; r < 4; r++)
        outp[(row + r) * (long)IN_ + col] = acc[i][j][r] + bv;
    }
  }
}

// ---------------- V transpose: qkv V-part -> vt[b][h][d(128)][VTK keys] ---------
__global__ __launch_bounds__(256)
void k_vtrans(const u16* __restrict__ qkv, u16* __restrict__ vt){
  const int b = blockIdx.z;
  const int h = blockIdx.y >> 1;
  const int d0 = (blockIdx.y & 1) * 64;
  const int k0 = blockIdx.x * 64;
  __shared__ u16 tile[64][72];
  const int t = threadIdx.x;
#pragma unroll
  for (int it = 0; it < 2; it++){
    const int idx = t + it*256;
    const int kk = idx >> 3;
    const int dd = (idx & 7) * 8;
    const int kabs = k0 + kk;
    union { bf16x8 v; u16 us[8]; } u;
    if (kabs <= 600)
      u.v = *(const bf16x8*)(qkv + ((long)b*TP1 + kabs)*3072 + 2048 + h*128 + d0 + dd);
    else {
#pragma unroll
      for (int j = 0; j < 8; j++) u.us[j] = 0;
    }
    *(bf16x8*)(&tile[kk][dd]) = u.v;
  }
  __syncthreads();
#pragma unroll
  for (int it = 0; it < 2; it++){
    const int idx = t + it*256;
    const int dd = idx >> 3;
    const int kc = (idx & 7) * 8;
    if (k0 + kc + 7 < VTK){
      union { uint4 o; u16 us[8]; } u;
#pragma unroll
      for (int j = 0; j < 8; j++) u.us[j] = tile[kc + j][dd];
      *(uint4*)(vt + ((long)(b*8 + h)*128 + d0 + dd)*VTK + k0 + kc) = u.o;
    }
  }
}

// ---------------- self-attention v6: MFMA row-sum + T13 defer-max ---------------
__global__ __launch_bounds__(256)
void k_sa_attn3(const u16* __restrict__ qkv, const u16* __restrict__ vt,
                u16* __restrict__ outp){
  const int id = blockIdx.x;
  const int g  = id & 127;
  const int qt = id >> 7;
  const int b = g >> 3, h = g & 7;
  const int w = threadIdx.x >> 6, l = threadIdx.x & 63;
  const int lr = l & 15, lg = l >> 4;
  const int q0 = qt * 64 + w * 16;
  const float scale = 0.08838834764831845f;
  const float slope = exp2f(-(float)(h + 1));

  __shared__ u16 Kl[2][4096];
  __shared__ u16 Vl[2][4096];
  __shared__ u16 Pl[4][16*40];
  __shared__ float cS[4][16];

  const long bb = (long)b * TP1;
  const u16* qptr = qkv + (bb + 1 + q0 + lr) * 3072 + h * 128 + lg * 8;
  bf16x8 aq[4];
#pragma unroll
  for (int kk = 0; kk < 4; kk++) aq[kk] = *(const bf16x8*)(qptr + kk * 32);

  // all-ones bf16 A-fragment for the row-sum MFMA
  bf16x8 ones;
#pragma unroll
  for (int i = 0; i < 8; i++) ones[i] = (__bf16)1.0f;

  const int kj0 = w*2, kj1 = w*2 + 1;
  const int kkey0 = kj0*4 + (l >> 4), kkey1 = kj1*4 + (l >> 4);
  const u16* kg0 = qkv + (bb + kkey0)*3072 + 1024 + h*128 + (((l&15) ^ (kkey0&7)))*8;
  const u16* kg1 = qkv + (bb + kkey1)*3072 + 1024 + h*128 + (((l&15) ^ (kkey1&7)))*8;
  const u16* vbase = vt + (long)(b*8 + h) * 128 * VTK;
  const int vd0 = kj0*16 + (l >> 2), vd1 = kj1*16 + (l >> 2);
  const u16* vg0 = vbase + (long)vd0*VTK + ((l&3) ^ ((vd0 >> 1) & 3))*8;
  const u16* vg1 = vbase + (long)vd1*VTK + ((l&3) ^ ((vd1 >> 1) & 3))*8;

#define STAGE(buf, kb) \
  gld_lds16(kg0 + (long)(kb)*3072, (void*)(Kl[buf] + kj0*512)); \
  gld_lds16(kg1 + (long)(kb)*3072, (void*)(Kl[buf] + kj1*512)); \
  gld_lds16(vg0 + (kb),            (void*)(Vl[buf] + kj0*512)); \
  gld_lds16(vg1 + (kb),            (void*)(Vl[buf] + kj1*512));

  f32x4 o[8] = {};
  float mrow[4] = {-1e30f, -1e30f, -1e30f, -1e30f};
  float lsumq = 0.f;                          // running denom for q = lr

  STAGE(0, 0);
  asm volatile("s_waitcnt vmcnt(0)" ::: "memory");
  BAR();

  for (int kt = 0; kt < 19; kt++){
    const int kb0 = kt * 32;
    const int cur = kt & 1;
    const bool st = (kt < 18);
    if (st){ STAGE(cur ^ 1, kb0 + 32); }
    f32x4 s0 = {}, s1 = {};
    __builtin_amdgcn_s_setprio(1);
#pragma unroll
    for (int kk = 0; kk < 4; kk++){
      const int sw = ((kk*4 + lg) ^ (lr & 7)) * 8;
      bf16x8 bk0 = *(const bf16x8*)(Kl[cur] + lr*128 + sw);
      bf16x8 bk1 = *(const bf16x8*)(Kl[cur] + (lr+16)*128 + sw);
      s0 = MM(aq[kk], bk0, s0);
      s1 = MM(aq[kk], bk1, s1);
    }
    __builtin_amdgcn_s_setprio(0);
    // masked+biased scores for all 4 rows (lane-local)
    float v0a[4], v1a[4];
#pragma unroll
    for (int r = 0; r < 4; r++){
      const int iq = q0 + lg * 4 + r;
      float v0 = s0[r] * scale, v1 = s1[r] * scale;
      const int k0a = kb0 + lr, k1a = kb0 + 16 + lr;
      if (k0a >= 601) v0 = -1e30f;
      else if (k0a > 0){
        const int j = k0a - 1, di = iq - j;
        const int st2 = di >= 0 ? di/25 : (-di-1)/25;
        v0 -= slope * (float)st2;
      }
      if (k1a >= 601) v1 = -1e30f;
      else {
        const int j = k1a - 1, di = iq - j;
        const int st2 = di >= 0 ? di/25 : (-di-1)/25;
        v1 -= slope * (float)st2;
      }
      v0a[r] = v0; v1a[r] = v1;
    }
    // T13 defer-max: if no score exceeds mrow+8 anywhere in the wave, keep old max
    bool okl = true;
#pragma unroll
    for (int r = 0; r < 4; r++)
      okl = okl && (v0a[r] <= mrow[r] + 8.f) && (v1a[r] <= mrow[r] + 8.f);
    float c = 1.f;
    bool resc = false;
    if (__all(okl)){
      // fast path: P = exp(v - m_old), bounded by e^8; no rescale
#pragma unroll
      for (int r = 0; r < 4; r++){
        Pl[w][(lg*4 + r)*40 + lr]      = f2bf(__expf(v0a[r] - mrow[r]));
        Pl[w][(lg*4 + r)*40 + 16 + lr] = f2bf(__expf(v1a[r] - mrow[r]));
      }
    } else {
#pragma unroll
      for (int r = 0; r < 4; r++){
        float mx = fmaxf(v0a[r], v1a[r]);
#pragma unroll
        for (int d = 8; d >= 1; d >>= 1) mx = fmaxf(mx, __shfl_xor(mx, d, 64));
        const float mnew = fmaxf(mrow[r], mx);
        const float corr = __expf(mrow[r] - mnew);
        mrow[r] = mnew;
        if (lr == 0) cS[w][lg*4 + r] = corr;
        Pl[w][(lg*4 + r)*40 + lr]      = f2bf(__expf(v0a[r] - mnew));
        Pl[w][(lg*4 + r)*40 + 16 + lr] = f2bf(__expf(v1a[r] - mnew));
      }
      c = cS[w][lr];
      resc = true;
    }
    const bf16x8 pa = *(const bf16x8*)(&Pl[w][lr*40 + lg*8]);
    // denom via matrix pipe: D[row][q=lr] = sum_k P[q][k] (rows identical)
    f32x4 zz = {0.f, 0.f, 0.f, 0.f};
    f32x4 sacc = MM(ones, pa, zz);
    lsumq = lsumq * c + sacc[0];
    __builtin_amdgcn_s_setprio(1);
#pragma unroll
    for (int dc = 0; dc < 8; dc++){
      const int d = dc*16 + lr;
      const bf16x8 va = *(const bf16x8*)(Vl[cur] + d*32 + ((lg ^ ((d >> 1) & 3))*8));
      if (resc){
#pragma unroll
        for (int rr = 0; rr < 4; rr++) o[dc][rr] *= c;
      }
      o[dc] = MM(va, pa, o[dc]);
    }
    __builtin_amdgcn_s_setprio(0);
    if (st){
      asm volatile("s_waitcnt vmcnt(0)" ::: "memory");
      BAR();
    }
  }
#undef STAGE
  const int tq = q0 + lr;
  if (tq < 600){
    const float inv = 1.f / lsumq;
    u16* op = outp + ((long)b*600 + tq) * 1024 + h * 128;
#pragma unroll
    for (int dc = 0; dc < 8; dc++){
      union { uint2 o8; u16 us[4]; } pk;
#pragma unroll
      for (int rr = 0; rr < 4; rr++) pk.us[rr] = f2bf(o[dc][rr] * inv);
      *(uint2*)(op + dc*16 + lg*4) = pk.o8;
    }
  }
}

// ---------------- cross-attention: exact 2-key softmax ---------------------------
__global__ __launch_bounds__(256)
void k_ca_attn(const u16* __restrict__ qca, const u16* __restrict__ kv,
               u16* __restrict__ outp){
  const int wid = blockIdx.x * 4 + (threadIdx.x >> 6);
  const int l = threadIdx.x & 63;
  if (wid >= MTOK) return;
  const int b = wid / 600, t = wid % 600;
  const u16* q  = qca + (long)wid * 1024;
  const u16* ka = kv + ((long)b * TP1) * 2048;
  const u16* km = kv + ((long)(b * TP1 + 1 + t)) * 2048;
  const float scale = 0.08838834764831845f;
#pragma unroll
  for (int h = 0; h < 8; h++){
    const int d = h*128 + l*2;
    const float q0 = bf2f(q[d]),  q1 = bf2f(q[d+1]);
    float s0 = q0*bf2f(ka[d]) + q1*bf2f(ka[d+1]);
    float s1 = q0*bf2f(km[d]) + q1*bf2f(km[d+1]);
#pragma unroll
    for (int dd = 32; dd >= 1; dd >>= 1){
      s0 += __shfl_xor(s0, dd, 64);
      s1 += __shfl_xor(s1, dd, 64);
    }
    s0 *= scale; s1 *= scale;
    const float mx = fmaxf(s0, s1);
    const float e0 = __expf(s0 - mx), e1 = __expf(s1 - mx);
    const float inv = 1.f / (e0 + e1);
    const float o0 = (e0*bf2f(ka[1024+d])   + e1*bf2f(km[1024+d]))   * inv;
    const float o1 = (e0*bf2f(ka[1024+d+1]) + e1*bf2f(km[1024+d+1])) * inv;
    const unsigned pack = (unsigned)f2bf(o0) | ((unsigned)f2bf(o1) << 16);
    *(unsigned*)(outp + (long)wid*1024 + d) = pack;
  }
}

// ------- residual-add + in-place LayerNorm (float4); optional xadpt mirror -------
__global__ __launch_bounds__(256)
void k_ln2(float* __restrict__ hf, const u16* __restrict__ sub,
           const float* __restrict__ g, const float* __restrict__ bb,
           u16* __restrict__ hbf, u16* __restrict__ xad){
  const long m = blockIdx.x;
  const int t = threadIdx.x;
  float4* r = (float4*)(hf + m*1024);
  float4 v = r[t];
  union { uint2 u; u16 us[4]; } sv;
  sv.u = *(const uint2*)(sub + m*1024 + t*4);
  v.x += bf2f(sv.us[0]); v.y += bf2f(sv.us[1]);
  v.z += bf2f(sv.us[2]); v.w += bf2f(sv.us[3]);
  float sum = v.x + v.y + v.z + v.w;
  float sumsq = v.x*v.x + v.y*v.y + v.z*v.z + v.w*v.w;
#pragma unroll
  for (int d = 32; d >= 1; d >>= 1){ sum += __shfl_xor(sum,d,64); sumsq += __shfl_xor(sumsq,d,64); }
  __shared__ float red[8];
  const int w = t >> 6;
  if ((t & 63) == 0){ red[w] = sum; red[4+w] = sumsq; }
  __syncthreads();
  sum   = red[0]+red[1]+red[2]+red[3];
  sumsq = red[4]+red[5]+red[6]+red[7];
  const float mu  = sum * (1.f/1024.f);
  const float var = sumsq * (1.f/1024.f) - mu*mu;
  const float rstd = rsqrtf(var + 1e-5f);
  const float4 gv = ((const float4*)g)[t];
  const float4 bv = ((const float4*)bb)[t];
  float4 y;
  y.x = (v.x - mu) * rstd * gv.x + bv.x;
  y.y = (v.y - mu) * rstd * gv.y + bv.y;
  y.z = (v.z - mu) * rstd * gv.z + bv.z;
  y.w = (v.w - mu) * rstd * gv.w + bv.w;
  r[t] = y;
  union { uint2 u; u16 us[4]; } p;
  p.us[0] = f2bf(y.x); p.us[1] = f2bf(y.y); p.us[2] = f2bf(y.z); p.us[3] = f2bf(y.w);
  *(uint2*)(hbf + m*1024 + t*4) = p.u;
  if (xad){
    const long bq = m / 600, tq = m % 600;
    *(uint2*)(xad + ((bq*TP1 + 1 + tq) << 10) + t*4) = p.u;
  }
}

// ---------------- small fp32 kernels ---------------------------------------------
__global__ void k_temb_sin(const int* __restrict__ ts, float* __restrict__ emb){
  const int b = blockIdx.x;
  const float t = (float)ts[b];
  for (int j = threadIdx.x; j < 1024; j += 256){
    const int jj = j < 512 ? j : j - 512;
    const float ex = expf(-9.210340371976184f * (float)jj / 511.0f);
    const float v = t * ex;
    emb[b*1024 + j] = (j < 512) ? sinf(v) : cosf(v);
  }
}

__global__ void k_te_mm(const float* __restrict__ in, const float* __restrict__ W,
                        const float* __restrict__ bv, float* __restrict__ outp,
                        int act, u16* __restrict__ xad, u16* __restrict__ mad){
  __shared__ float row[1024];
  const int b = blockIdx.y;
  for (int k = threadIdx.x; k < 1024; k += 256) row[k] = in[b*1024 + k];
  __syncthreads();
  const int n = blockIdx.x*256 + threadIdx.x;
  const float* wr = W + (long)n*1024;
  float s = 0.f;
  for (int k = 0; k < 1024; k += 4){
    const float4 w4 = *(const float4*)(wr + k);
    s += row[k]*w4.x + row[k+1]*w4.y + row[k+2]*w4.z + row[k+3]*w4.w;
  }
  s += bv[n];
  if (act) s = s / (1.f + expf(-s));   // silu
  outp[b*1024 + n] = s;
  if (xad){
    const u16 h = f2bf(s);
    xad[((long)b*TP1)*1024 + n] = h;
    mad[((long)b*TP1)*1024 + n] = h;
  }
}

// ---------------- data movement / conversion -------------------------------------
__global__ void k_convert_weights(const float* __restrict__ sqkv, const float* __restrict__ swo,
                                  const float* __restrict__ cqkv, const float* __restrict__ cwo,
                                  const float* __restrict__ fw1,  const float* __restrict__ fw2,
                                  u16* __restrict__ wbuf){
  const long idx = ((long)blockIdx.x*256 + threadIdx.x) * 8;
  const float* src; long off;
  if      (idx <  3145728L){ src = sqkv; off = idx; }
  else if (idx <  4194304L){ src = swo;  off = idx -  3145728L; }
  else if (idx <  7340032L){ src = cqkv; off = idx -  4194304L; }
  else if (idx <  8388608L){ src = cwo;  off = idx -  7340032L; }
  else if (idx < 12582912L){ src = fw1;  off = idx -  8388608L; }
  else                     { src = fw2;  off = idx - 12582912L; }
  const float4 a = *(const float4*)(src + off);
  const float4 c = *(const float4*)(src + off + 4);
  uint4 o;
  o.x = (unsigned)f2bf(a.x) | ((unsigned)f2bf(a.y) << 16);
  o.y = (unsigned)f2bf(a.z) | ((unsigned)f2bf(a.w) << 16);
  o.z = (unsigned)f2bf(c.x) | ((unsigned)f2bf(c.y) << 16);
  o.w = (unsigned)f2bf(c.z) | ((unsigned)f2bf(c.w) << 16);
  *(uint4*)(wbuf + idx) = o;
}

__global__ void k_convert_wout(const float* __restrict__ src, u16* __restrict__ dst){
  const int i = blockIdx.x*256 + threadIdx.x;   // 131072 total
  const int row = i >> 10;
  dst[i] = (row < IN_) ? f2bf(src[i]) : (u16)0;
}

__global__ void k_convert_x(const float* __restrict__ x, u16* __restrict__ dst){
  const int i = blockIdx.x*256 + threadIdx.x;   // MPAD*64 = 622592
  const int row = i >> 6, c = i & 63;
  float v = 0.f;
  if (row < MTOK && c < IN_) v = x[(long)row*IN_ + c];
  dst[i] = f2bf(v);
}

__global__ void k_convert_win(const float* __restrict__ wi, u16* __restrict__ dst){
  const int i = blockIdx.x*256 + threadIdx.x;   // 1024*64 = 65536
  const int row = i >> 6, c = i & 63;
  dst[i] = (c < IN_) ? f2bf(wi[(long)row*IN_ + c]) : (u16)0;
}

__global__ void k_build_memadpt(const float* __restrict__ mem, u16* __restrict__ mad){
  const long i = ((long)blockIdx.x*256 + threadIdx.x) * 8;
  const long tok = i >> 10, col = i & 1023;
  const long b = tok / 600, s = tok % 600;
  const float4 a = *(const float4*)(mem + i);
  const float4 c = *(const float4*)(mem + i + 4);
  uint4 o;
  o.x = (unsigned)f2bf(a.x) | ((unsigned)f2bf(a.y) << 16);
  o.y = (unsigned)f2bf(a.z) | ((unsigned)f2bf(a.w) << 16);
  o.z = (unsigned)f2bf(c.x) | ((unsigned)f2bf(c.y) << 16);
  o.w = (unsigned)f2bf(c.z) | ((unsigned)f2bf(c.w) << 16);
  *(uint4*)(mad + ((b*TP1 + 1 + s) << 10) + col) = o;
}

// ---------------- host-side launch -----------------------------------------------
extern "C" void kernel_launch(void* const* d_in, const int* in_sizes, int n_in,
                              void* d_out, int out_size, void* d_ws, size_t ws_size,
                              hipStream_t stream){
  const float* x        = (const float*)d_in[0];
  const float* memory   = (const float*)d_in[1];
  const int*   tsteps   = (const int*)  d_in[2];
  const float* pe       = (const float*)d_in[3];
  const float* W_in     = (const float*)d_in[5];
  const float* b_in     = (const float*)d_in[6];
  const float* te_W1    = (const float*)d_in[7];
  const float* te_b1    = (const float*)d_in[8];
  const float* te_W2    = (const float*)d_in[9];
  const float* te_b2    = (const float*)d_in[10];
  const float* sa_Wqkv  = (const float*)d_in[11];
  const float* sa_bqkv  = (const float*)d_in[12];
  const float* sa_Wo    = (const float*)d_in[13];
  const float* sa_bo    = (const float*)d_in[14];
  const float* ca_Wqkv  = (const float*)d_in[15];
  const float* ca_bqkv  = (const float*)d_in[16];
  const float* ca_Wo    = (const float*)d_in[17];
  const float* ca_bo    = (const float*)d_in[18];
  const float* ff_W1    = (const float*)d_in[19];
  const float* ff_b1    = (const float*)d_in[20];
  const float* ff_W2    = (const float*)d_in[21];
  const float* ff_b2    = (const float*)d_in[22];
  const float* ln1_g    = (const float*)d_in[23];
  const float* ln2_g    = (const float*)d_in[24];
  const float* ln3_g    = (const float*)d_in[25];
  const float* ln1_b    = (const float*)d_in[26];
  const float* ln2_b    = (const float*)d_in[27];
  const float* ln3_b    = (const float*)d_in[28];
  const float* W_out    = (const float*)d_in[29];
  const float* b_out    = (const float*)d_in[30];

  char* ws = (char*)d_ws;   // ~311 MB used
  float* h_f    = (float*)(ws + 0);            //  9600x1024 f32
  u16*   h_bf   = (u16*)  (ws + 39321600);     //  9600x1024 bf16
  u16*   attn_bf= (u16*)  (ws + 58982400);     //  9600x1024
  u16*   xadpt  = (u16*)  (ws + 78643200);     //  9616x1024
  u16*   madpt  = (u16*)  (ws + 98336768);     //  9616x1024
  u16*   qkv    = (u16*)  (ws + 118030336);    //  MPADx3072
  u16*   ffb    = (u16*)  (ws + 177799168);    //  MPADx4096
  u16*   wbuf   = (u16*)  (ws + 257490944);    //  16.7M bf16
  u16*   sub_bf = (u16*)  (ws + 291045376);    //  MPADx1024 bf16 (GEMM C for residual)
  float* temb_a = (float*)(ws + 177799168);    //  alias ffb (prologue only)
  float* temb_b = (float*)(ws + 177864704);
  u16*   vtg    = (u16*)  (ws + 177799168 + 262144); // alias ffb (dead before FF1)
  u16*   x_bf   = wbuf;                        //  alias wbuf (prologue only) MPADx64
  u16*   win_bf = wbuf + 622592;               //  1024x64
  u16*   wout_bf= wbuf;                        //  reuse after layer loop

  u16* qca  = qkv;                             // 9600x1024 (token-major)
  u16* kvca = qkv + (long)MPAD * 1024;         // MPADx2048 (adapter-major)

  // time-embed + adapter + input projection (MFMA path)
  k_temb_sin<<<dim3(16), dim3(256), 0, stream>>>(tsteps, temb_a);
  k_te_mm<<<dim3(4,16), dim3(256), 0, stream>>>(temb_a, te_W1, te_b1, temb_b, 1, (u16*)nullptr, (u16*)nullptr);
  k_te_mm<<<dim3(4,16), dim3(256), 0, stream>>>(temb_b, te_W2, te_b2, temb_a, 0, xadpt, madpt);
  k_build_memadpt<<<dim3(4800), dim3(256), 0, stream>>>(memory, madpt);
  k_convert_x<<<dim3(2432), dim3(256), 0, stream>>>(x, x_bf);
  k_convert_win<<<dim3(256), dim3(256), 0, stream>>>(W_in, win_bf);
  k_gemm_in<<<dim3(8,76), dim3(256), 0, stream>>>(x_bf, win_bf, b_in, pe, h_f, h_bf, xadpt);

  for (int l = 0; l < L_; l++){
    k_convert_weights<<<dim3(8192), dim3(256), 0, stream>>>(
        sa_Wqkv + (long)l*3145728, sa_Wo + (long)l*1048576,
        ca_Wqkv + (long)l*3145728, ca_Wo + (long)l*1048576,
        ff_W1 + (long)l*4194304,  ff_W2 + (long)l*4194304, wbuf);
    // --- self attention (xadpt maintained by k_gemm_in / ln3 of prev layer) ---
    k_gemm256<0><<<dim3(12,38), dim3(512), 0, stream>>>(xadpt, wbuf, sa_bqkv + l*3072, (void*)qkv, 3072, 1024);
    k_vtrans<<<dim3(10,16,16), dim3(256), 0, stream>>>(qkv, vtg);
    k_sa_attn3<<<dim3(1280), dim3(256), 0, stream>>>(qkv, vtg, attn_bf);
    k_gemm_n128<0><<<dim3(8,76), dim3(256), 0, stream>>>(attn_bf, wbuf + 3145728, sa_bo + l*1024, (void*)sub_bf, 1024, 1024);
    k_ln2<<<dim3(9600), dim3(256), 0, stream>>>(h_f, sub_bf, ln1_g + l*1024, ln1_b + l*1024, h_bf, (u16*)nullptr);
    // --- cross attention (adapter + diagonal only) ---
    k_gemm_n128<0><<<dim3(8,76), dim3(256), 0, stream>>>(h_bf, wbuf + 4194304, ca_bqkv + l*3072, (void*)qca, 1024, 1024);
    k_gemm_n128<0><<<dim3(16,76), dim3(256), 0, stream>>>(madpt, wbuf + 4194304 + 1048576, ca_bqkv + l*3072 + 1024, (void*)kvca, 2048, 1024);
    k_ca_attn<<<dim3(2400), dim3(256), 0, stream>>>(qca, kvca, attn_bf);
    k_gemm_n128<0><<<dim3(8,76), dim3(256), 0, stream>>>(attn_bf, wbuf + 7340032, ca_bo + l*1024, (void*)sub_bf, 1024, 1024);
    k_ln2<<<dim3(9600), dim3(256), 0, stream>>>(h_f, sub_bf, ln2_g + l*1024, ln2_b + l*1024, h_bf, (u16*)nullptr);
    // --- feed forward ---
    k_gemm256<1><<<dim3(16,38), dim3(512), 0, stream>>>(h_bf, wbuf + 8388608, ff_b1 + l*4096, (void*)ffb, 4096, 1024);
    k_gemm_n128<0><<<dim3(8,76), dim3(256), 0, stream>>>(ffb, wbuf + 12582912, ff_b2 + l*1024, (void*)sub_bf, 1024, 4096);
    k_ln2<<<dim3(9600), dim3(256), 0, stream>>>(h_f, sub_bf, ln3_g + l*1024, ln3_b + l*1024, h_bf, xadpt);
  }
  k_convert_wout<<<dim3(512), dim3(256), 0, stream>>>(W_out, wout_bf);
  k_gemm_out<<<dim3(1,75), dim3(256), 0, stream>>>(h_bf, wout_bf, b_out, (float*)d_out);
}